// Round 7
// baseline (123.485 us; speedup 1.0000x reference)
//
#include <hip/hip_runtime.h>
#include <math.h>

// Problem constants
#define LL 3600
#define NODES 6400

typedef __attribute__((ext_vector_type(8))) _Float16 half8;
typedef __attribute__((ext_vector_type(4))) float f32x4;

// ---------------- fp16 helper ----------------
__device__ __forceinline__ unsigned short f2h(float f) {
    union { _Float16 h; unsigned short u; } cv;
    cv.h = (_Float16)f;
    return cv.u;
}

#define GLOAD16(gp, lp) __builtin_amdgcn_global_load_lds( \
    (const __attribute__((address_space(1))) unsigned int*)(const void*)(gp), \
    (__attribute__((address_space(3))) unsigned int*)(void*)(lp), 16, 0, 0)

// ---------------- block reduce (wave shuffle + 4-way LDS) ----------------
__device__ __forceinline__ void block_reduce_sum2(float a, float b, float* red, float& ra, float& rb) {
    #pragma unroll
    for (int o = 32; o > 0; o >>= 1) { a += __shfl_xor(a, o, 64); b += __shfl_xor(b, o, 64); }
    int w = threadIdx.x >> 6, l = threadIdx.x & 63;
    if (l == 0) { red[w] = a; red[4 + w] = b; }
    __syncthreads();
    ra = red[0] + red[1] + red[2] + red[3];
    rb = red[4] + red[5] + red[6] + red[7];
    __syncthreads();
}

// ================= MEGA PREP KERNEL =================
// blocks [0,2304): W1T  | [2304,2944): W2T | [2944,4480): W3T
// [4480]: AeS | [4481,4581): adj | [4581,10981): tcn0
__global__ __launch_bounds__(256) void prep_kernel(
    const float* __restrict__ wg1, const float* __restrict__ wf1, const float* __restrict__ ws1,
    const float* __restrict__ sWv, const float* __restrict__ dWv,
    const float* __restrict__ sWq, const float* __restrict__ saq,
    const float* __restrict__ sWk, const float* __restrict__ sak,
    const float* __restrict__ dWq, const float* __restrict__ daq,
    const float* __restrict__ dWk, const float* __restrict__ dak,
    const float* __restrict__ fW1, const float* __restrict__ fW2, const float* __restrict__ fW3,
    const float* __restrict__ sWe, const float* __restrict__ sae,
    const float* __restrict__ E1, const float* __restrict__ E2,
    const float* __restrict__ x,
    const float* __restrict__ wg0, const float* __restrict__ bg0,
    const float* __restrict__ wf0, const float* __restrict__ bf0,
    const float* __restrict__ ws0, const float* __restrict__ bs0,
    const float* __restrict__ lg0, const float* __restrict__ lb0,
    unsigned short* __restrict__ W1h,
    unsigned short* __restrict__ W2h,
    unsigned short* __restrict__ W3h,
    float* __restrict__ AeS,
    int* __restrict__ cnt, int* __restrict__ idxs, float* __restrict__ logv,
    unsigned short* __restrict__ Xh) {
    __shared__ float smem[22];   // tcn0: xs[14] + red[8]
    int bid = blockIdx.x;
    int tid = threadIdx.x;

    if (bid < 2304) {
        // ---- W1T[n][k]: n = which*256+o, k = tt*256+i; val = w1[o][i][tt]
        int idx = bid * 256 + tid;
        int n = idx / 768, k = idx % 768;
        int which = n >> 8, o = n & 255;
        int tt = k >> 8, i = k & 255;
        const float* w = which == 0 ? wg1 : (which == 1 ? wf1 : ws1);
        W1h[idx] = f2h(w[(o * 256 + i) * 3 + tt]);
    } else if (bid < 2944) {
        // ---- W2T[n][k], n in [0,640), k in [0,256)
        int idx = (bid - 2304) * 256 + tid;
        int n = idx / 256, k = idx % 256;
        float v = 0.f;
        if (n < 256) v = sWv[k * 256 + n];
        else if (n < 512) v = dWv[k * 256 + (n - 256)];
        else if (n < 544) {
            int j = n - 512, g = j >> 3, h = j & 7;
            const float* Wm = g == 0 ? sWq : (g == 1 ? sWk : (g == 2 ? dWq : dWk));
            const float* am = g == 0 ? saq : (g == 1 ? sak : (g == 2 ? daq : dak));
            float s = 0.f;
            for (int d = 0; d < 32; d++) s += Wm[k * 256 + h * 32 + d] * am[h * 32 + d];
            v = s;
        }
        W2h[idx] = f2h(v);
    } else if (bid < 4480) {
        // ---- W3T[n][k], n in [0,768), k in [0,512)
        int idx = (bid - 2944) * 256 + tid;
        int n = idx / 512, k = idx % 512;
        float v = 0.f;
        if (k < 256) {
            if (n < 256) v = fW1[k * 256 + n];
            else if (n < 512) v = fW2[k * 256 + (n - 256)];
        } else {
            int c = k - 256;
            if (n < 256) v = fW1[c * 256 + n];
            else if (n >= 512) v = fW3[c * 256 + (n - 512)];
        }
        W3h[idx] = f2h(v);
    } else if (bid == 4480) {
        if (tid < 16) {
            int cc = tid / 8, h = tid % 8;
            float s = 0.f;
            for (int d = 0; d < 32; d++) s += sWe[cc * 256 + h * 32 + d] * sae[h * 32 + d];
            AeS[tid] = s;
        }
    } else if (bid < 4581) {
        // ---- adjacency: one wave per row
        int n = ((bid - 4481) * 256 + tid) >> 6;
        int lane = tid & 63;
        if (n >= 400) return;
        float e1[10];
        #pragma unroll
        for (int k = 0; k < 10; k++) e1[k] = E1[n * 10 + k];
        float p[7];
        #pragma unroll
        for (int i = 0; i < 7; i++) {
            int j = i * 64 + lane;
            if (j < 400) {
                float s = 0.f;
                #pragma unroll
                for (int k = 0; k < 10; k++) s += e1[k] * E2[j * 10 + k];
                p[i] = fmaxf(s, 0.f);
            } else p[i] = -1e30f;
        }
        float mx = -1e30f;
        #pragma unroll
        for (int i = 0; i < 7; i++) mx = fmaxf(mx, p[i]);
        #pragma unroll
        for (int o = 32; o > 0; o >>= 1) mx = fmaxf(mx, __shfl_xor(mx, o, 64));
        float sum = 0.f;
        #pragma unroll
        for (int i = 0; i < 7; i++) {
            int j = i * 64 + lane;
            if (j < 400) { p[i] = expf(p[i] - mx); sum += p[i]; }
        }
        #pragma unroll
        for (int o = 32; o > 0; o >>= 1) sum += __shfl_xor(sum, o, 64);
        float inv = 1.f / sum;
        float m[7];
        #pragma unroll
        for (int i = 0; i < 7; i++) {
            int j = i * 64 + lane;
            if (j < 400) { p[i] *= inv; m[i] = p[i]; }
            else m[i] = -1e30f;
        }
        for (int it = 0; it < 15; ++it) {
            float lm = m[0];
            #pragma unroll
            for (int i = 1; i < 7; i++) lm = fmaxf(lm, m[i]);
            float gm = lm;
            #pragma unroll
            for (int o = 32; o > 0; o >>= 1) gm = fmaxf(gm, __shfl_xor(gm, o, 64));
            unsigned long long msk = __ballot(lm == gm);
            int first = (int)(__ffsll((long long)msk)) - 1;
            if (lane == first) {
                #pragma unroll
                for (int i = 0; i < 7; i++) {
                    if (m[i] == gm) { m[i] = -1e30f; break; }
                }
            }
        }
        float kth = m[0];
        #pragma unroll
        for (int i = 1; i < 7; i++) kth = fmaxf(kth, m[i]);
        #pragma unroll
        for (int o = 32; o > 0; o >>= 1) kth = fmaxf(kth, __shfl_xor(kth, o, 64));
        int base = 0;
        #pragma unroll
        for (int i = 0; i < 7; i++) {
            int j = i * 64 + lane;
            bool pred = (j < 400) && (p[i] >= kth);
            unsigned long long msk = __ballot(pred);
            int pre = __popcll(msk & ((lane == 63) ? 0x7fffffffffffffffull : ((1ull << lane) - 1)));
            if (pred) {
                int pos = base + pre;
                if (pos < 64) {
                    idxs[n * 64 + pos] = j;
                    logv[n * 64 + pos] = logf(fmaxf(p[i], 1e-12f));
                }
            }
            base += __popcll(msk);
        }
        if (lane == 0) cnt[n] = base < 64 ? base : 64;
    } else {
        // ---- TCN layer 0
        int node = bid - 4581;
        int o = tid;
        float* xs = smem;        // [7][2]
        float* red = smem + 14;  // [8]
        if (o < 14) { int t = 5 + o / 2, c = o & 1; xs[(t - 5) * 2 + c] = x[(size_t)(node * 12 + t) * 2 + c]; }
        __syncthreads();
        float wg[6], wf[6], wsv[6];
        for (int i = 0; i < 6; i++) { wg[i] = wg0[o * 6 + i]; wf[i] = wf0[o * 6 + i]; wsv[i] = ws0[o * 6 + i]; }
        float bg = bg0[o], bf = bf0[o], bs = bs0[o];
        float gln = lg0[o], bln = lb0[o];
        for (int tt = 0; tt < 3; tt++) {
            int t = 7 + 2 * tt;
            float g = bg, f = bf, s = bs;
            for (int k = 0; k < 3; k++) {
                int ti = t - 2 + k - 5;
                for (int c = 0; c < 2; c++) {
                    float xv = xs[ti * 2 + c];
                    g += wg[c * 3 + k] * xv;
                    f += wf[c * 3 + k] * xv;
                    s += wsv[c * 3 + k] * xv;
                }
            }
            float gate = 1.f / (1.f + expf(-g));
            float y = gate * f + (1.f - gate) * s;
            float sum, sq;
            block_reduce_sum2(y, y * y, red, sum, sq);
            float mean = sum * (1.f / 256.f);
            float var = sq * (1.f / 256.f) - mean * mean;
            float v = (y - mean) * rsqrtf(var + 1e-5f) * gln + bln;
            v = fmaxf(v, 0.f);
            Xh[(size_t)node * 768 + tt * 256 + o] = f2h(v);
        }
    }
}

// ---------------- fp16 MFMA GEMM, 64x64 tile, BK=32, 3-stage counted-vmcnt pipeline ----------------
// C(MxN) = A(MxK) @ BT(NxK)^T. Grid: GX col-blocks x 100 row-blocks, bijective XCD swizzle.
// 4 waves as 2x2; each wave 32x32 (2x2 16x16 frags).
template<int K, int LDC, int GX>
__global__ __launch_bounds__(256, 4) void gemm_f16(
    const unsigned short* __restrict__ A,
    const unsigned short* __restrict__ BT,
    float* __restrict__ C) {
    __shared__ __align__(16) unsigned short lA[3][64 * 32];    // 12KB
    __shared__ __align__(16) unsigned short lB[3][64 * 32];    // 12KB -> 24KB total
    int tid = threadIdx.x;
    int lane = tid & 63;
    int w = tid >> 6;
    int wm = w >> 1, wn = w & 1;
    int r = lane & 15, g4 = lane >> 4;

    // bijective XCD swizzle (m204); NWG % 8 == 0 for all our grids
    constexpr int NWG = GX * 100;
    constexpr int Q = NWG / 8, R = NWG % 8;
    int flat = blockIdx.y * GX + blockIdx.x;
    int xcd = flat & 7, idx = flat >> 3;
    int nf = (xcd < R ? xcd * (Q + 1) : R * (Q + 1) + (xcd - R) * Q) + idx;
    int col0 = (nf % GX) * 64;
    int row0 = (nf / GX) * 64;

    f32x4 acc[2][2] = {};

    // staging: linear LDS dest; global source k-slot pre-swizzled (rule #21)
    int rS = tid >> 2;                  // staged row 0..63
    int slot = tid & 3;                 // 16B slot within row
    int tk = (slot ^ (rS & 3)) * 8;     // swizzled k offset (halves)

#define STAGE(sel, kk) do { \
    GLOAD16(A + (size_t)(row0 + rS) * K + (kk) + tk, &lA[sel][tid * 8]); \
    GLOAD16(BT + (size_t)(col0 + rS) * K + (kk) + tk, &lB[sel][tid * 8]); \
} while (0)

    int sw = (g4 ^ (r & 3)) << 3;       // swizzled read slot (halves)

#define COMPUTE(cur) do { \
    half8 a_[2], b_[2]; \
    _Pragma("unroll") \
    for (int mi = 0; mi < 2; ++mi) \
        a_[mi] = *(const half8*)&lA[cur][(wm * 32 + mi * 16 + r) * 32 + sw]; \
    _Pragma("unroll") \
    for (int ni = 0; ni < 2; ++ni) \
        b_[ni] = *(const half8*)&lB[cur][(wn * 32 + ni * 16 + r) * 32 + sw]; \
    _Pragma("unroll") \
    for (int mi = 0; mi < 2; ++mi) \
        _Pragma("unroll") \
        for (int ni = 0; ni < 2; ++ni) \
            acc[mi][ni] = __builtin_amdgcn_mfma_f32_16x16x32_f16(a_[mi], b_[ni], acc[mi][ni], 0, 0, 0); \
} while (0)

    constexpr int NT = K >> 5;
    STAGE(0, 0);
    STAGE(1, 32);
    // main loop: tile t's loads awaited with vmcnt(2) (t+1's 2 loads stay in flight);
    // raw barrier (no compiler vmcnt(0) drain); stage t+2 after barrier (its buffer
    // was last ds_read in iter t-1, already register-consumed before this barrier).
    for (int t = 0; t < NT - 1; ++t) {
        asm volatile("s_waitcnt vmcnt(2)" ::: "memory");
        __builtin_amdgcn_s_barrier();
        if (t + 2 < NT) STAGE((t + 2) % 3, (t + 2) * 32);
        COMPUTE(t % 3);
    }
    asm volatile("s_waitcnt vmcnt(0)" ::: "memory");
    __builtin_amdgcn_s_barrier();
    COMPUTE((NT - 1) % 3);
#undef STAGE
#undef COMPUTE

    #pragma unroll
    for (int mi = 0; mi < 2; ++mi) {
        #pragma unroll
        for (int ni = 0; ni < 2; ++ni) {
            int rowb = row0 + wm * 32 + mi * 16 + g4 * 4;
            int colb = col0 + wn * 32 + ni * 16 + r;
            #pragma unroll
            for (int j = 0; j < 4; ++j)
                C[(size_t)(rowb + j) * LDC + colb] = acc[mi][ni][j];
        }
    }
}

// ---------------- layer-1 epilogue -> HLh ----------------
__global__ __launch_bounds__(256) void epi1_kernel(
    const float* __restrict__ Y1, const float* __restrict__ x,
    const float* __restrict__ bg1, const float* __restrict__ bf1, const float* __restrict__ bs1,
    const float* __restrict__ lg, const float* __restrict__ lb,
    const float* __restrict__ wsk, const float* __restrict__ bsk,
    unsigned short* __restrict__ HLh) {
    int node = blockIdx.x, o = threadIdx.x;
    __shared__ float red[8];
    size_t base = (size_t)node * 768;
    float g = Y1[base + o] + bg1[o];
    float f = Y1[base + 256 + o] + bf1[o];
    float s = Y1[base + 512 + o] + bs1[o];
    float gate = 1.f / (1.f + expf(-g));
    float y = gate * f + (1.f - gate) * s;
    float sum, sq;
    block_reduce_sum2(y, y * y, red, sum, sq);
    float mean = sum * (1.f / 256.f);
    float var = sq * (1.f / 256.f) - mean * mean;
    float v = (y - mean) * rsqrtf(var + 1e-5f) * lg[o] + lb[o];
    v = fmaxf(v, 0.f);
    float x0 = x[(size_t)(node * 12 + 11) * 2];
    float x1 = x[(size_t)(node * 12 + 11) * 2 + 1];
    float res = x0 * wsk[o] + x1 * wsk[256 + o] + bsk[o];
    HLh[(size_t)node * 256 + o] = f2h(v + res);
}

// ---------------- fused GAT (fixed + adaptive) -> U ----------------
__global__ __launch_bounds__(256) void gat_kernel(
    const float* __restrict__ Y2, const float* __restrict__ ef,
    const int* __restrict__ fei, const float* __restrict__ AeS,
    const int* __restrict__ cnt, const int* __restrict__ idxs, const float* __restrict__ logv,
    unsigned short* __restrict__ Uh) {
    int tid = threadIdx.x;
    if (blockIdx.x < NODES) {
        // ---- fixed-graph GAT -> U cols [0,256)
        int node = blockIdx.x;
        int b = node / 400, n = node % 400;
        __shared__ int snd[9];
        __shared__ float sv[9][8];
        __shared__ float al[9][8];
        if (tid < 9) snd[tid] = fei[LL + n * 9 + tid];
        __syncthreads();
        if (tid < 72) {
            int j = tid / 8, h = tid % 8;
            int l = n * 9 + j;
            float e0 = ef[((size_t)b * LL + l) * 2];
            float e1 = ef[((size_t)b * LL + l) * 2 + 1];
            float ae = e0 * AeS[h] + e1 * AeS[8 + h];
            float aq = Y2[(size_t)node * 640 + 512 + h];
            float ak = Y2[((size_t)(b * 400 + snd[j])) * 640 + 520 + h];
            float s = aq + ak + ae;
            s = s > 0.f ? s : 0.2f * s;
            sv[j][h] = s;
        }
        __syncthreads();
        if (tid < 8) {
            int h = tid;
            float mx = -1e30f;
            for (int j = 0; j < 9; j++) mx = fmaxf(mx, sv[j][h]);
            float den = 0.f;
            for (int j = 0; j < 9; j++) { float e = expf(sv[j][h] - mx); al[j][h] = e; den += e; }
            den = fmaxf(den, 1e-12f);
            for (int j = 0; j < 9; j++) al[j][h] /= den;
        }
        __syncthreads();
        int h = tid >> 5, d = tid & 31;
        float acc = 0.f;
        for (int j = 0; j < 9; j++)
            acc += al[j][h] * Y2[((size_t)(b * 400 + snd[j])) * 640 + h * 32 + d];
        float e = acc > 0.f ? acc : (expf(acc) - 1.f);
        Uh[(size_t)node * 512 + tid] = f2h(e);
    } else {
        // ---- adaptive attention -> U cols [256,512)
        int node = blockIdx.x - NODES;
        int b = node / 400, n = node % 400;
        __shared__ int jidx[64];
        __shared__ float jlog[64];
        __shared__ float sc[64][8];
        __shared__ float alb[64][8];
        int c = cnt[n];
        if (tid < c) { jidx[tid] = idxs[n * 64 + tid]; jlog[tid] = logv[n * 64 + tid]; }
        __syncthreads();
        for (int e = tid; e < c * 8; e += 256) {
            int j = e / 8, h = e % 8;
            float aq = Y2[(size_t)node * 640 + 528 + h];
            float ak = Y2[((size_t)(b * 400 + jidx[j])) * 640 + 536 + h];
            float s = aq + ak;
            s = s > 0.f ? s : 0.2f * s;
            sc[j][h] = s + jlog[j];
        }
        __syncthreads();
        if (tid < 8) {
            int h = tid; float mx = -1e30f;
            for (int j = 0; j < c; j++) mx = fmaxf(mx, sc[j][h]);
            float den = 0.f;
            for (int j = 0; j < c; j++) { float e = expf(sc[j][h] - mx); alb[j][h] = e; den += e; }
            for (int j = 0; j < c; j++) alb[j][h] /= den;
        }
        __syncthreads();
        int h = tid >> 5, d = tid & 31;
        float acc = 0.f;
        for (int j = 0; j < c; j++)
            acc += alb[j][h] * Y2[((size_t)(b * 400 + jidx[j])) * 640 + 256 + h * 32 + d];
        float e = acc > 0.f ? acc : (expf(acc) - 1.f);
        Uh[(size_t)node * 512 + 256 + tid] = f2h(e);
    }
}

// ---------------- final fuse + output projection ----------------
__global__ __launch_bounds__(256) void final_kernel(
    const float* __restrict__ Y3,
    const float* __restrict__ fb1, const float* __restrict__ fb2, const float* __restrict__ fb3,
    const float* __restrict__ Wo, const float* __restrict__ bo,
    float* __restrict__ out) {
    int node = blockIdx.x, o = threadIdx.x;
    __shared__ float red[12];
    size_t base = (size_t)node * 768;
    float g = 1.f / (1.f + expf(-(Y3[base + o] + fb1[o])));
    float a2 = Y3[base + 256 + o] + fb2[o];
    float a3 = Y3[base + 512 + o] + fb3[o];
    float fused = tanhf(g * a2 + (1.f - g) * a3);
    float v0 = fused * Wo[o * 3 + 0];
    float v1 = fused * Wo[o * 3 + 1];
    float v2 = fused * Wo[o * 3 + 2];
    #pragma unroll
    for (int off = 32; off > 0; off >>= 1) {
        v0 += __shfl_xor(v0, off, 64);
        v1 += __shfl_xor(v1, off, 64);
        v2 += __shfl_xor(v2, off, 64);
    }
    int w = o >> 6, l = o & 63;
    if (l == 0) { red[w] = v0; red[4 + w] = v1; red[8 + w] = v2; }
    __syncthreads();
    if (o < 3) {
        float s = red[o * 4] + red[o * 4 + 1] + red[o * 4 + 2] + red[o * 4 + 3];
        out[(size_t)node * 3 + o] = s + bo[o];
    }
}

// ---------------- launcher ----------------
extern "C" void kernel_launch(void* const* d_in, const int* in_sizes, int n_in,
                              void* d_out, int out_size, void* d_ws, size_t ws_size,
                              hipStream_t stream) {
    const float* x   = (const float*)d_in[0];
    const float* ef  = (const float*)d_in[1];
    const int*   fei = (const int*)d_in[2];
    const float* wg0 = (const float*)d_in[3];
    const float* bg0 = (const float*)d_in[4];
    const float* wf0 = (const float*)d_in[5];
    const float* bf0 = (const float*)d_in[6];
    const float* ws0 = (const float*)d_in[7];
    const float* bs0 = (const float*)d_in[8];
    const float* ln0g = (const float*)d_in[9];
    const float* ln0b = (const float*)d_in[10];
    const float* wg1 = (const float*)d_in[11];
    const float* bg1 = (const float*)d_in[12];
    const float* wf1 = (const float*)d_in[13];
    const float* bf1 = (const float*)d_in[14];
    const float* ws1 = (const float*)d_in[15];
    const float* bs1 = (const float*)d_in[16];
    const float* ln1g = (const float*)d_in[17];
    const float* ln1b = (const float*)d_in[18];
    const float* wsk = (const float*)d_in[19];
    const float* bsk = (const float*)d_in[20];
    const float* sWq = (const float*)d_in[21];
    const float* sWk = (const float*)d_in[22];
    const float* sWv = (const float*)d_in[23];
    const float* sWe = (const float*)d_in[24];
    const float* saq = (const float*)d_in[25];
    const float* sak = (const float*)d_in[26];
    const float* sae = (const float*)d_in[27];
    const float* dWq = (const float*)d_in[28];
    const float* dWk = (const float*)d_in[29];
    const float* dWv = (const float*)d_in[30];
    const float* daq = (const float*)d_in[31];
    const float* dak = (const float*)d_in[32];
    const float* E1  = (const float*)d_in[33];
    const float* E2  = (const float*)d_in[34];
    const float* fW1 = (const float*)d_in[35];
    const float* fb1 = (const float*)d_in[36];
    const float* fW2 = (const float*)d_in[37];
    const float* fb2 = (const float*)d_in[38];
    const float* fW3 = (const float*)d_in[39];
    const float* fb3 = (const float*)d_in[40];
    const float* Wo  = (const float*)d_in[41];
    const float* bo  = (const float*)d_in[42];
    float* out = (float*)d_out;

    char* b = (char*)d_ws;
    unsigned short* Xh  = (unsigned short*)(b + 0);          // 9,830,400
    float*          Y1  = (float*)(b + 9830400);             // 19,660,800 (shared w/ Y2, Y3)
    unsigned short* HLh = (unsigned short*)(b + 29491200);   // 3,276,800
    unsigned short* Uh  = (unsigned short*)(b + 32768000);   // 6,553,600
    unsigned short* W1h = (unsigned short*)(b + 39321600);   // 1,179,648
    unsigned short* W2h = (unsigned short*)(b + 40501248);   // 327,680
    unsigned short* W3h = (unsigned short*)(b + 40828928);   // 786,432
    float*          AES = (float*)(b + 41615360);            // 64
    float*          LOGV= (float*)(b + 41615616);            // 102,400
    int*            CNT = (int*)(b + 41718016);              // 1,600
    int*            IDX = (int*)(b + 41719616);              // 102,400
    float*          Y2  = Y1;   // G2 output after Y1 consumed by epi1
    float*          Y3  = Y1;   // G3 output after Y2 consumed by gat

    // all input-only work in ONE launch
    prep_kernel<<<10981, 256, 0, stream>>>(
        wg1, wf1, ws1,
        sWv, dWv, sWq, saq, sWk, sak, dWq, daq, dWk, dak,
        fW1, fW2, fW3, sWe, sae, E1, E2,
        x, wg0, bg0, wf0, bf0, ws0, bs0, ln0g, ln0b,
        W1h, W2h, W3h, AES,
        CNT, IDX, LOGV, Xh);

    // G1: Y1 = X @ W1  (M=6400, N=768, K=768)
    gemm_f16<768, 768, 12><<<dim3(12, 100), 256, 0, stream>>>(Xh, W1h, Y1);

    epi1_kernel<<<NODES, 256, 0, stream>>>(Y1, x, bg1, bf1, bs1, ln1g, ln1b, wsk, bsk, HLh);

    // G2: Y2 = HL @ W2 (M=6400, N=640, K=256)
    gemm_f16<256, 640, 10><<<dim3(10, 100), 256, 0, stream>>>(HLh, W2h, Y2);

    // fused attention stages -> U
    gat_kernel<<<2 * NODES, 256, 0, stream>>>(Y2, ef, fei, AES, CNT, IDX, LOGV, Uh);

    // G3: Y3 = U @ W3 (M=6400, N=768, K=512)
    gemm_f16<512, 768, 12><<<dim3(12, 100), 256, 0, stream>>>(Uh, W3h, Y3);

    final_kernel<<<NODES, 256, 0, stream>>>(Y3, fb1, fb2, fb3, Wo, bo, out);
}

// Round 8
// 108.615 us; speedup vs baseline: 1.1369x; 1.1369x over previous
//
#include <hip/hip_runtime.h>
#include <math.h>

// Problem constants
#define LL 3600
#define NODES 6400

typedef __attribute__((ext_vector_type(8))) _Float16 half8;
typedef __attribute__((ext_vector_type(4))) float f32x4;

// ---------------- fp16 helpers ----------------
__device__ __forceinline__ unsigned short f2h(float f) {
    union { _Float16 h; unsigned short u; } cv;
    cv.h = (_Float16)f;
    return cv.u;
}
__device__ __forceinline__ float h2f(unsigned short u) {
    union { unsigned short u; _Float16 h; } cv;
    cv.u = u;
    return (float)cv.h;
}

#define GLOAD16(gp, lp) __builtin_amdgcn_global_load_lds( \
    (const __attribute__((address_space(1))) unsigned int*)(const void*)(gp), \
    (__attribute__((address_space(3))) unsigned int*)(void*)(lp), 16, 0, 0)

// ---------------- block reduce (wave shuffle + 4-way LDS) ----------------
__device__ __forceinline__ void block_reduce_sum2(float a, float b, float* red, float& ra, float& rb) {
    #pragma unroll
    for (int o = 32; o > 0; o >>= 1) { a += __shfl_xor(a, o, 64); b += __shfl_xor(b, o, 64); }
    int w = threadIdx.x >> 6, l = threadIdx.x & 63;
    if (l == 0) { red[w] = a; red[4 + w] = b; }
    __syncthreads();
    ra = red[0] + red[1] + red[2] + red[3];
    rb = red[4] + red[5] + red[6] + red[7];
    __syncthreads();
}

// ================= MEGA PREP KERNEL =================
// blocks [0,2304): W1T  | [2304,2944): W2T | [2944,4480): W3T
// [4480]: AeS | [4481,4581): adj | [4581,10981): tcn0
__global__ __launch_bounds__(256) void prep_kernel(
    const float* __restrict__ wg1, const float* __restrict__ wf1, const float* __restrict__ ws1,
    const float* __restrict__ sWv, const float* __restrict__ dWv,
    const float* __restrict__ sWq, const float* __restrict__ saq,
    const float* __restrict__ sWk, const float* __restrict__ sak,
    const float* __restrict__ dWq, const float* __restrict__ daq,
    const float* __restrict__ dWk, const float* __restrict__ dak,
    const float* __restrict__ fW1, const float* __restrict__ fW2, const float* __restrict__ fW3,
    const float* __restrict__ sWe, const float* __restrict__ sae,
    const float* __restrict__ E1, const float* __restrict__ E2,
    const float* __restrict__ x,
    const float* __restrict__ wg0, const float* __restrict__ bg0,
    const float* __restrict__ wf0, const float* __restrict__ bf0,
    const float* __restrict__ ws0, const float* __restrict__ bs0,
    const float* __restrict__ lg0, const float* __restrict__ lb0,
    unsigned short* __restrict__ W1h,
    unsigned short* __restrict__ W2h,
    unsigned short* __restrict__ W3h,
    float* __restrict__ AeS,
    int* __restrict__ cnt, int* __restrict__ idxs, float* __restrict__ logv,
    unsigned short* __restrict__ Xh) {
    __shared__ float smem[22];   // tcn0: xs[14] + red[8]
    int bid = blockIdx.x;
    int tid = threadIdx.x;

    if (bid < 2304) {
        // ---- W1T[n][k]: n = which*256+o, k = tt*256+i; val = w1[o][i][tt]
        int idx = bid * 256 + tid;
        int n = idx / 768, k = idx % 768;
        int which = n >> 8, o = n & 255;
        int tt = k >> 8, i = k & 255;
        const float* w = which == 0 ? wg1 : (which == 1 ? wf1 : ws1);
        W1h[idx] = f2h(w[(o * 256 + i) * 3 + tt]);
    } else if (bid < 2944) {
        // ---- W2T[n][k], n in [0,640), k in [0,256)
        int idx = (bid - 2304) * 256 + tid;
        int n = idx / 256, k = idx % 256;
        float v = 0.f;
        if (n < 256) v = sWv[k * 256 + n];
        else if (n < 512) v = dWv[k * 256 + (n - 256)];
        else if (n < 544) {
            int j = n - 512, g = j >> 3, h = j & 7;
            const float* Wm = g == 0 ? sWq : (g == 1 ? sWk : (g == 2 ? dWq : dWk));
            const float* am = g == 0 ? saq : (g == 1 ? sak : (g == 2 ? daq : dak));
            float s = 0.f;
            for (int d = 0; d < 32; d++) s += Wm[k * 256 + h * 32 + d] * am[h * 32 + d];
            v = s;
        }
        W2h[idx] = f2h(v);
    } else if (bid < 4480) {
        // ---- W3T[n][k], n in [0,768), k in [0,512)
        int idx = (bid - 2944) * 256 + tid;
        int n = idx / 512, k = idx % 512;
        float v = 0.f;
        if (k < 256) {
            if (n < 256) v = fW1[k * 256 + n];
            else if (n < 512) v = fW2[k * 256 + (n - 256)];
        } else {
            int c = k - 256;
            if (n < 256) v = fW1[c * 256 + n];
            else if (n >= 512) v = fW3[c * 256 + (n - 512)];
        }
        W3h[idx] = f2h(v);
    } else if (bid == 4480) {
        if (tid < 16) {
            int cc = tid / 8, h = tid % 8;
            float s = 0.f;
            for (int d = 0; d < 32; d++) s += sWe[cc * 256 + h * 32 + d] * sae[h * 32 + d];
            AeS[tid] = s;
        }
    } else if (bid < 4581) {
        // ---- adjacency: one wave per row
        int n = ((bid - 4481) * 256 + tid) >> 6;
        int lane = tid & 63;
        if (n >= 400) return;
        float e1[10];
        #pragma unroll
        for (int k = 0; k < 10; k++) e1[k] = E1[n * 10 + k];
        float p[7];
        #pragma unroll
        for (int i = 0; i < 7; i++) {
            int j = i * 64 + lane;
            if (j < 400) {
                float s = 0.f;
                #pragma unroll
                for (int k = 0; k < 10; k++) s += e1[k] * E2[j * 10 + k];
                p[i] = fmaxf(s, 0.f);
            } else p[i] = -1e30f;
        }
        float mx = -1e30f;
        #pragma unroll
        for (int i = 0; i < 7; i++) mx = fmaxf(mx, p[i]);
        #pragma unroll
        for (int o = 32; o > 0; o >>= 1) mx = fmaxf(mx, __shfl_xor(mx, o, 64));
        float sum = 0.f;
        #pragma unroll
        for (int i = 0; i < 7; i++) {
            int j = i * 64 + lane;
            if (j < 400) { p[i] = expf(p[i] - mx); sum += p[i]; }
        }
        #pragma unroll
        for (int o = 32; o > 0; o >>= 1) sum += __shfl_xor(sum, o, 64);
        float inv = 1.f / sum;
        float m[7];
        #pragma unroll
        for (int i = 0; i < 7; i++) {
            int j = i * 64 + lane;
            if (j < 400) { p[i] *= inv; m[i] = p[i]; }
            else m[i] = -1e30f;
        }
        for (int it = 0; it < 15; ++it) {
            float lm = m[0];
            #pragma unroll
            for (int i = 1; i < 7; i++) lm = fmaxf(lm, m[i]);
            float gm = lm;
            #pragma unroll
            for (int o = 32; o > 0; o >>= 1) gm = fmaxf(gm, __shfl_xor(gm, o, 64));
            unsigned long long msk = __ballot(lm == gm);
            int first = (int)(__ffsll((long long)msk)) - 1;
            if (lane == first) {
                #pragma unroll
                for (int i = 0; i < 7; i++) {
                    if (m[i] == gm) { m[i] = -1e30f; break; }
                }
            }
        }
        float kth = m[0];
        #pragma unroll
        for (int i = 1; i < 7; i++) kth = fmaxf(kth, m[i]);
        #pragma unroll
        for (int o = 32; o > 0; o >>= 1) kth = fmaxf(kth, __shfl_xor(kth, o, 64));
        int base = 0;
        #pragma unroll
        for (int i = 0; i < 7; i++) {
            int j = i * 64 + lane;
            bool pred = (j < 400) && (p[i] >= kth);
            unsigned long long msk = __ballot(pred);
            int pre = __popcll(msk & ((lane == 63) ? 0x7fffffffffffffffull : ((1ull << lane) - 1)));
            if (pred) {
                int pos = base + pre;
                if (pos < 64) {
                    idxs[n * 64 + pos] = j;
                    logv[n * 64 + pos] = logf(fmaxf(p[i], 1e-12f));
                }
            }
            base += __popcll(msk);
        }
        if (lane == 0) cnt[n] = base < 64 ? base : 64;
    } else {
        // ---- TCN layer 0
        int node = bid - 4581;
        int o = tid;
        float* xs = smem;        // [7][2]
        float* red = smem + 14;  // [8]
        if (o < 14) { int t = 5 + o / 2, c = o & 1; xs[(t - 5) * 2 + c] = x[(size_t)(node * 12 + t) * 2 + c]; }
        __syncthreads();
        float wg[6], wf[6], wsv[6];
        for (int i = 0; i < 6; i++) { wg[i] = wg0[o * 6 + i]; wf[i] = wf0[o * 6 + i]; wsv[i] = ws0[o * 6 + i]; }
        float bg = bg0[o], bf = bf0[o], bs = bs0[o];
        float gln = lg0[o], bln = lb0[o];
        for (int tt = 0; tt < 3; tt++) {
            int t = 7 + 2 * tt;
            float g = bg, f = bf, s = bs;
            for (int k = 0; k < 3; k++) {
                int ti = t - 2 + k - 5;
                for (int c = 0; c < 2; c++) {
                    float xv = xs[ti * 2 + c];
                    g += wg[c * 3 + k] * xv;
                    f += wf[c * 3 + k] * xv;
                    s += wsv[c * 3 + k] * xv;
                }
            }
            float gate = 1.f / (1.f + expf(-g));
            float y = gate * f + (1.f - gate) * s;
            float sum, sq;
            block_reduce_sum2(y, y * y, red, sum, sq);
            float mean = sum * (1.f / 256.f);
            float var = sq * (1.f / 256.f) - mean * mean;
            float v = (y - mean) * rsqrtf(var + 1e-5f) * gln + bln;
            v = fmaxf(v, 0.f);
            Xh[(size_t)node * 768 + tt * 256 + o] = f2h(v);
        }
    }
}

// ---------------- fp16 MFMA GEMM, 64x64 tile, BK=32, 3-stage counted-vmcnt pipeline ----------------
// C(MxN fp16) = A(MxK) @ BT(NxK)^T. Grid: GX col-blocks x 100 row-blocks, bijective XCD swizzle.
template<int K, int LDC, int GX>
__global__ __launch_bounds__(256, 4) void gemm_f16(
    const unsigned short* __restrict__ A,
    const unsigned short* __restrict__ BT,
    unsigned short* __restrict__ C) {
    __shared__ __align__(16) unsigned short lA[3][64 * 32];    // 12KB
    __shared__ __align__(16) unsigned short lB[3][64 * 32];    // 12KB -> 24KB total
    int tid = threadIdx.x;
    int lane = tid & 63;
    int w = tid >> 6;
    int wm = w >> 1, wn = w & 1;
    int r = lane & 15, g4 = lane >> 4;

    // bijective XCD swizzle (m204); NWG % 8 == 0 for all our grids
    constexpr int NWG = GX * 100;
    constexpr int Q = NWG / 8, R = NWG % 8;
    int flat = blockIdx.y * GX + blockIdx.x;
    int xcd = flat & 7, idx = flat >> 3;
    int nf = (xcd < R ? xcd * (Q + 1) : R * (Q + 1) + (xcd - R) * Q) + idx;
    int col0 = (nf % GX) * 64;
    int row0 = (nf / GX) * 64;

    f32x4 acc[2][2] = {};

    // staging: linear LDS dest; global source k-slot pre-swizzled (rule #21)
    int rS = tid >> 2;                  // staged row 0..63
    int slot = tid & 3;                 // 16B slot within row
    int tk = (slot ^ (rS & 3)) * 8;     // swizzled k offset (halves)

#define STAGE(sel, kk) do { \
    GLOAD16(A + (size_t)(row0 + rS) * K + (kk) + tk, &lA[sel][tid * 8]); \
    GLOAD16(BT + (size_t)(col0 + rS) * K + (kk) + tk, &lB[sel][tid * 8]); \
} while (0)

    int sw = (g4 ^ (r & 3)) << 3;       // swizzled read slot (halves)

#define COMPUTE(cur) do { \
    half8 a_[2], b_[2]; \
    _Pragma("unroll") \
    for (int mi = 0; mi < 2; ++mi) \
        a_[mi] = *(const half8*)&lA[cur][(wm * 32 + mi * 16 + r) * 32 + sw]; \
    _Pragma("unroll") \
    for (int ni = 0; ni < 2; ++ni) \
        b_[ni] = *(const half8*)&lB[cur][(wn * 32 + ni * 16 + r) * 32 + sw]; \
    _Pragma("unroll") \
    for (int mi = 0; mi < 2; ++mi) \
        _Pragma("unroll") \
        for (int ni = 0; ni < 2; ++ni) \
            acc[mi][ni] = __builtin_amdgcn_mfma_f32_16x16x32_f16(a_[mi], b_[ni], acc[mi][ni], 0, 0, 0); \
} while (0)

    constexpr int NT = K >> 5;
    STAGE(0, 0);
    STAGE(1, 32);
    for (int t = 0; t < NT - 1; ++t) {
        asm volatile("s_waitcnt vmcnt(2)" ::: "memory");
        __builtin_amdgcn_s_barrier();
        if (t + 2 < NT) STAGE((t + 2) % 3, (t + 2) * 32);
        COMPUTE(t % 3);
    }
    asm volatile("s_waitcnt vmcnt(0)" ::: "memory");
    __builtin_amdgcn_s_barrier();
    COMPUTE((NT - 1) % 3);
#undef STAGE
#undef COMPUTE

    #pragma unroll
    for (int mi = 0; mi < 2; ++mi) {
        #pragma unroll
        for (int ni = 0; ni < 2; ++ni) {
            int rowb = row0 + wm * 32 + mi * 16 + g4 * 4;
            int colb = col0 + wn * 32 + ni * 16 + r;
            #pragma unroll
            for (int j = 0; j < 4; ++j)
                C[(size_t)(rowb + j) * LDC + colb] = f2h(acc[mi][ni][j]);
        }
    }
}

// ---------------- layer-1 epilogue (fp16 in) -> HLh ----------------
__global__ __launch_bounds__(256) void epi1_kernel(
    const unsigned short* __restrict__ Y1, const float* __restrict__ x,
    const float* __restrict__ bg1, const float* __restrict__ bf1, const float* __restrict__ bs1,
    const float* __restrict__ lg, const float* __restrict__ lb,
    const float* __restrict__ wsk, const float* __restrict__ bsk,
    unsigned short* __restrict__ HLh) {
    int node = blockIdx.x, o = threadIdx.x;
    __shared__ float red[8];
    size_t base = (size_t)node * 768;
    float g = h2f(Y1[base + o]) + bg1[o];
    float f = h2f(Y1[base + 256 + o]) + bf1[o];
    float s = h2f(Y1[base + 512 + o]) + bs1[o];
    float gate = 1.f / (1.f + expf(-g));
    float y = gate * f + (1.f - gate) * s;
    float sum, sq;
    block_reduce_sum2(y, y * y, red, sum, sq);
    float mean = sum * (1.f / 256.f);
    float var = sq * (1.f / 256.f) - mean * mean;
    float v = (y - mean) * rsqrtf(var + 1e-5f) * lg[o] + lb[o];
    v = fmaxf(v, 0.f);
    float x0 = x[(size_t)(node * 12 + 11) * 2];
    float x1 = x[(size_t)(node * 12 + 11) * 2 + 1];
    float res = x0 * wsk[o] + x1 * wsk[256 + o] + bsk[o];
    HLh[(size_t)node * 256 + o] = f2h(v + res);
}

// ---------------- fused GAT (fixed + adaptive), fp16 Y2, parallel softmax -> Uh ----------------
__global__ __launch_bounds__(256) void gat_kernel(
    const unsigned short* __restrict__ Y2, const float* __restrict__ ef,
    const int* __restrict__ fei, const float* __restrict__ AeS,
    const int* __restrict__ cnt, const int* __restrict__ idxs, const float* __restrict__ logv,
    unsigned short* __restrict__ Uh) {
    int tid = threadIdx.x;
    if (blockIdx.x < NODES) {
        // ---- fixed-graph GAT -> U cols [0,256)
        int node = blockIdx.x;
        int b = node / 400, n = node % 400;
        __shared__ int snd[9];
        __shared__ float sv[9][8];
        __shared__ float al[9][8];
        __shared__ float invden[8];
        if (tid < 9) snd[tid] = fei[LL + n * 9 + tid];
        __syncthreads();
        if (tid < 72) {
            int j = tid / 8, h = tid % 8;
            int l = n * 9 + j;
            float e0 = ef[((size_t)b * LL + l) * 2];
            float e1 = ef[((size_t)b * LL + l) * 2 + 1];
            float ae = e0 * AeS[h] + e1 * AeS[8 + h];
            float aq = h2f(Y2[(size_t)node * 640 + 512 + h]);
            float ak = h2f(Y2[((size_t)(b * 400 + snd[j])) * 640 + 520 + h]);
            float s = aq + ak + ae;
            s = s > 0.f ? s : 0.2f * s;
            sv[j][h] = s;
        }
        __syncthreads();
        if (tid < 8) {
            int h = tid;
            float mx = -1e30f;
            #pragma unroll
            for (int j = 0; j < 9; j++) mx = fmaxf(mx, sv[j][h]);
            float den = 0.f;
            #pragma unroll
            for (int j = 0; j < 9; j++) { float e = expf(sv[j][h] - mx); al[j][h] = e; den += e; }
            invden[h] = 1.f / fmaxf(den, 1e-12f);
        }
        __syncthreads();
        int h = tid >> 5;
        float acc = 0.f;
        #pragma unroll
        for (int j = 0; j < 9; j++)
            acc += al[j][h] * h2f(Y2[((size_t)(b * 400 + snd[j])) * 640 + tid]);
        acc *= invden[h];
        float e = acc > 0.f ? acc : (expf(acc) - 1.f);
        Uh[(size_t)node * 512 + tid] = f2h(e);
    } else {
        // ---- adaptive attention -> U cols [256,512)
        int node = blockIdx.x - NODES;
        int b = node / 400, n = node % 400;
        __shared__ int jidx[64];
        __shared__ float jlog[64];
        __shared__ float sc[64][8];
        __shared__ float alb[64][8];
        __shared__ float red8[8][8];
        __shared__ float mxd[8];
        __shared__ float invden[8];
        int c = cnt[n];
        if (tid < c) { jidx[tid] = idxs[n * 64 + tid]; jlog[tid] = logv[n * 64 + tid]; }
        __syncthreads();
        for (int e = tid; e < c * 8; e += 256) {
            int j = e / 8, h = e % 8;
            float aq = h2f(Y2[(size_t)node * 640 + 528 + h]);
            float ak = h2f(Y2[((size_t)(b * 400 + jidx[j])) * 640 + 536 + h]);
            float s = aq + ak;
            s = s > 0.f ? s : 0.2f * s;
            sc[j][h] = s + jlog[j];
        }
        __syncthreads();
        // parallel max: 8 h x 8 j-groups
        if (tid < 64) {
            int h = tid >> 3, grp = tid & 7;
            float mx = -1e30f;
            for (int j = grp; j < c; j += 8) mx = fmaxf(mx, sc[j][h]);
            red8[h][grp] = mx;
        }
        __syncthreads();
        if (tid < 8) {
            float mx = red8[tid][0];
            #pragma unroll
            for (int g = 1; g < 8; g++) mx = fmaxf(mx, red8[tid][g]);
            mxd[tid] = mx;
        }
        __syncthreads();
        // parallel exp + partial sum
        if (tid < 64) {
            int h = tid >> 3, grp = tid & 7;
            float mx = mxd[h], s = 0.f;
            for (int j = grp; j < c; j += 8) { float e = expf(sc[j][h] - mx); alb[j][h] = e; s += e; }
            red8[h][grp] = s;
        }
        __syncthreads();
        if (tid < 8) {
            float s = 0.f;
            #pragma unroll
            for (int g = 0; g < 8; g++) s += red8[tid][g];
            invden[tid] = 1.f / s;
        }
        __syncthreads();
        int h = tid >> 5;
        float acc = 0.f;
        for (int j = 0; j < c; j++)
            acc += alb[j][h] * h2f(Y2[((size_t)(b * 400 + jidx[j])) * 640 + 256 + tid]);
        acc *= invden[h];
        float e = acc > 0.f ? acc : (expf(acc) - 1.f);
        Uh[(size_t)node * 512 + 256 + tid] = f2h(e);
    }
}

// ---------------- final fuse + output projection (fp16 in) ----------------
__global__ __launch_bounds__(256) void final_kernel(
    const unsigned short* __restrict__ Y3,
    const float* __restrict__ fb1, const float* __restrict__ fb2, const float* __restrict__ fb3,
    const float* __restrict__ Wo, const float* __restrict__ bo,
    float* __restrict__ out) {
    int node = blockIdx.x, o = threadIdx.x;
    __shared__ float red[12];
    size_t base = (size_t)node * 768;
    float g = 1.f / (1.f + expf(-(h2f(Y3[base + o]) + fb1[o])));
    float a2 = h2f(Y3[base + 256 + o]) + fb2[o];
    float a3 = h2f(Y3[base + 512 + o]) + fb3[o];
    float fused = tanhf(g * a2 + (1.f - g) * a3);
    float v0 = fused * Wo[o * 3 + 0];
    float v1 = fused * Wo[o * 3 + 1];
    float v2 = fused * Wo[o * 3 + 2];
    #pragma unroll
    for (int off = 32; off > 0; off >>= 1) {
        v0 += __shfl_xor(v0, off, 64);
        v1 += __shfl_xor(v1, off, 64);
        v2 += __shfl_xor(v2, off, 64);
    }
    int w = o >> 6, l = o & 63;
    if (l == 0) { red[w] = v0; red[4 + w] = v1; red[8 + w] = v2; }
    __syncthreads();
    if (o < 3) {
        float s = red[o * 4] + red[o * 4 + 1] + red[o * 4 + 2] + red[o * 4 + 3];
        out[(size_t)node * 3 + o] = s + bo[o];
    }
}

// ---------------- launcher ----------------
extern "C" void kernel_launch(void* const* d_in, const int* in_sizes, int n_in,
                              void* d_out, int out_size, void* d_ws, size_t ws_size,
                              hipStream_t stream) {
    const float* x   = (const float*)d_in[0];
    const float* ef  = (const float*)d_in[1];
    const int*   fei = (const int*)d_in[2];
    const float* wg0 = (const float*)d_in[3];
    const float* bg0 = (const float*)d_in[4];
    const float* wf0 = (const float*)d_in[5];
    const float* bf0 = (const float*)d_in[6];
    const float* ws0 = (const float*)d_in[7];
    const float* bs0 = (const float*)d_in[8];
    const float* ln0g = (const float*)d_in[9];
    const float* ln0b = (const float*)d_in[10];
    const float* wg1 = (const float*)d_in[11];
    const float* bg1 = (const float*)d_in[12];
    const float* wf1 = (const float*)d_in[13];
    const float* bf1 = (const float*)d_in[14];
    const float* ws1 = (const float*)d_in[15];
    const float* bs1 = (const float*)d_in[16];
    const float* ln1g = (const float*)d_in[17];
    const float* ln1b = (const float*)d_in[18];
    const float* wsk = (const float*)d_in[19];
    const float* bsk = (const float*)d_in[20];
    const float* sWq = (const float*)d_in[21];
    const float* sWk = (const float*)d_in[22];
    const float* sWv = (const float*)d_in[23];
    const float* sWe = (const float*)d_in[24];
    const float* saq = (const float*)d_in[25];
    const float* sak = (const float*)d_in[26];
    const float* sae = (const float*)d_in[27];
    const float* dWq = (const float*)d_in[28];
    const float* dWk = (const float*)d_in[29];
    const float* dWv = (const float*)d_in[30];
    const float* daq = (const float*)d_in[31];
    const float* dak = (const float*)d_in[32];
    const float* E1  = (const float*)d_in[33];
    const float* E2  = (const float*)d_in[34];
    const float* fW1 = (const float*)d_in[35];
    const float* fb1 = (const float*)d_in[36];
    const float* fW2 = (const float*)d_in[37];
    const float* fb2 = (const float*)d_in[38];
    const float* fW3 = (const float*)d_in[39];
    const float* fb3 = (const float*)d_in[40];
    const float* Wo  = (const float*)d_in[41];
    const float* bo  = (const float*)d_in[42];
    float* out = (float*)d_out;

    char* b = (char*)d_ws;
    unsigned short* Xh  = (unsigned short*)(b + 0);          // 9,830,400
    unsigned short* Yh  = (unsigned short*)(b + 9830400);    // 9,830,400 (Y1/Y2/Y3 fp16, reused)
    unsigned short* HLh = (unsigned short*)(b + 19660800);   // 3,276,800
    unsigned short* Uh  = (unsigned short*)(b + 22937600);   // 6,553,600
    unsigned short* W1h = (unsigned short*)(b + 29491200);   // 1,179,648
    unsigned short* W2h = (unsigned short*)(b + 30670848);   // 327,680
    unsigned short* W3h = (unsigned short*)(b + 30998528);   // 786,432
    float*          AES = (float*)(b + 31784960);            // 64 (+pad)
    float*          LOGV= (float*)(b + 31785216);            // 102,400
    int*            CNT = (int*)(b + 31887616);              // 1,600
    int*            IDX = (int*)(b + 31889216);              // 102,400

    // all input-only work in ONE launch
    prep_kernel<<<10981, 256, 0, stream>>>(
        wg1, wf1, ws1,
        sWv, dWv, sWq, saq, sWk, sak, dWq, daq, dWk, dak,
        fW1, fW2, fW3, sWe, sae, E1, E2,
        x, wg0, bg0, wf0, bf0, ws0, bs0, ln0g, ln0b,
        W1h, W2h, W3h, AES,
        CNT, IDX, LOGV, Xh);

    // G1: Y1 = X @ W1  (M=6400, N=768, K=768) -> fp16
    gemm_f16<768, 768, 12><<<dim3(12, 100), 256, 0, stream>>>(Xh, W1h, Yh);

    epi1_kernel<<<NODES, 256, 0, stream>>>(Yh, x, bg1, bf1, bs1, ln1g, ln1b, wsk, bsk, HLh);

    // G2: Y2 = HL @ W2 (M=6400, N=640, K=256) -> fp16 (reuses Yh after epi1)
    gemm_f16<256, 640, 10><<<dim3(10, 100), 256, 0, stream>>>(HLh, W2h, Yh);

    // fused attention stages -> U
    gat_kernel<<<2 * NODES, 256, 0, stream>>>(Yh, ef, fei, AES, CNT, IDX, LOGV, Uh);

    // G3: Y3 = U @ W3 (M=6400, N=768, K=512) -> fp16 (reuses Yh after gat)
    gemm_f16<512, 768, 12><<<dim3(12, 100), 256, 0, stream>>>(Uh, W3h, Yh);

    final_kernel<<<NODES, 256, 0, stream>>>(Yh, fb1, fb2, fb3, Wo, bo, out);
}

// Round 9
// 100.131 us; speedup vs baseline: 1.2332x; 1.0847x over previous
//
#include <hip/hip_runtime.h>
#include <math.h>

// Problem constants
#define LL 3600
#define NODES 6400

typedef __attribute__((ext_vector_type(8))) _Float16 half8;
typedef __attribute__((ext_vector_type(4))) float f32x4;

// ---------------- fp16 helpers ----------------
__device__ __forceinline__ unsigned short f2h(float f) {
    union { _Float16 h; unsigned short u; } cv;
    cv.h = (_Float16)f;
    return cv.u;
}
__device__ __forceinline__ float h2f(unsigned short u) {
    union { unsigned short u; _Float16 h; } cv;
    cv.u = u;
    return (float)cv.h;
}

#define GLOAD16(gp, lp) __builtin_amdgcn_global_load_lds( \
    (const __attribute__((address_space(1))) unsigned int*)(const void*)(gp), \
    (__attribute__((address_space(3))) unsigned int*)(void*)(lp), 16, 0, 0)

// ================= MEGA PREP KERNEL =================
// blocks [0,2304): W1T | [2304,2944): W2T | [2944,4480): W3T
// [4480]: AeS | [4481,4581): adj | [4581,6181): tcn0 (4 nodes/block, 1 wave each)
__global__ __launch_bounds__(256) void prep_kernel(
    const float* __restrict__ wg1, const float* __restrict__ wf1, const float* __restrict__ ws1,
    const float* __restrict__ sWv, const float* __restrict__ dWv,
    const float* __restrict__ sWq, const float* __restrict__ saq,
    const float* __restrict__ sWk, const float* __restrict__ sak,
    const float* __restrict__ dWq, const float* __restrict__ daq,
    const float* __restrict__ dWk, const float* __restrict__ dak,
    const float* __restrict__ fW1, const float* __restrict__ fW2, const float* __restrict__ fW3,
    const float* __restrict__ sWe, const float* __restrict__ sae,
    const float* __restrict__ E1, const float* __restrict__ E2,
    const float* __restrict__ x,
    const float* __restrict__ wg0, const float* __restrict__ bg0,
    const float* __restrict__ wf0, const float* __restrict__ bf0,
    const float* __restrict__ ws0, const float* __restrict__ bs0,
    const float* __restrict__ lg0, const float* __restrict__ lb0,
    unsigned short* __restrict__ W1h,
    unsigned short* __restrict__ W2h,
    unsigned short* __restrict__ W3h,
    float* __restrict__ AeS,
    int* __restrict__ cnt, int* __restrict__ idxs, float* __restrict__ logv,
    unsigned short* __restrict__ Xh) {
    int bid = blockIdx.x;
    int tid = threadIdx.x;

    if (bid < 2304) {
        // ---- W1T[n][k]: n = which*256+o, k = tt*256+i; val = w1[o][i][tt]
        int idx = bid * 256 + tid;
        int n = idx / 768, k = idx % 768;
        int which = n >> 8, o = n & 255;
        int tt = k >> 8, i = k & 255;
        const float* w = which == 0 ? wg1 : (which == 1 ? wf1 : ws1);
        W1h[idx] = f2h(w[(o * 256 + i) * 3 + tt]);
    } else if (bid < 2944) {
        // ---- W2T[n][k], n in [0,640), k in [0,256)
        int idx = (bid - 2304) * 256 + tid;
        int n = idx / 256, k = idx % 256;
        float v = 0.f;
        if (n < 256) v = sWv[k * 256 + n];
        else if (n < 512) v = dWv[k * 256 + (n - 256)];
        else if (n < 544) {
            int j = n - 512, g = j >> 3, h = j & 7;
            const float* Wm = g == 0 ? sWq : (g == 1 ? sWk : (g == 2 ? dWq : dWk));
            const float* am = g == 0 ? saq : (g == 1 ? sak : (g == 2 ? daq : dak));
            float s = 0.f;
            for (int d = 0; d < 32; d++) s += Wm[k * 256 + h * 32 + d] * am[h * 32 + d];
            v = s;
        }
        W2h[idx] = f2h(v);
    } else if (bid < 4480) {
        // ---- W3T[n][k], n in [0,768), k in [0,512)
        int idx = (bid - 2944) * 256 + tid;
        int n = idx / 512, k = idx % 512;
        float v = 0.f;
        if (k < 256) {
            if (n < 256) v = fW1[k * 256 + n];
            else if (n < 512) v = fW2[k * 256 + (n - 256)];
        } else {
            int c = k - 256;
            if (n < 256) v = fW1[c * 256 + n];
            else if (n >= 512) v = fW3[c * 256 + (n - 512)];
        }
        W3h[idx] = f2h(v);
    } else if (bid == 4480) {
        if (tid < 16) {
            int cc = tid / 8, h = tid % 8;
            float s = 0.f;
            for (int d = 0; d < 32; d++) s += sWe[cc * 256 + h * 32 + d] * sae[h * 32 + d];
            AeS[tid] = s;
        }
    } else if (bid < 4581) {
        // ---- adjacency: one wave per row
        int n = ((bid - 4481) * 256 + tid) >> 6;
        int lane = tid & 63;
        if (n >= 400) return;
        float e1[10];
        #pragma unroll
        for (int k = 0; k < 10; k++) e1[k] = E1[n * 10 + k];
        float p[7];
        #pragma unroll
        for (int i = 0; i < 7; i++) {
            int j = i * 64 + lane;
            if (j < 400) {
                float s = 0.f;
                #pragma unroll
                for (int k = 0; k < 10; k++) s += e1[k] * E2[j * 10 + k];
                p[i] = fmaxf(s, 0.f);
            } else p[i] = -1e30f;
        }
        float mx = -1e30f;
        #pragma unroll
        for (int i = 0; i < 7; i++) mx = fmaxf(mx, p[i]);
        #pragma unroll
        for (int o = 32; o > 0; o >>= 1) mx = fmaxf(mx, __shfl_xor(mx, o, 64));
        float sum = 0.f;
        #pragma unroll
        for (int i = 0; i < 7; i++) {
            int j = i * 64 + lane;
            if (j < 400) { p[i] = expf(p[i] - mx); sum += p[i]; }
        }
        #pragma unroll
        for (int o = 32; o > 0; o >>= 1) sum += __shfl_xor(sum, o, 64);
        float inv = 1.f / sum;
        float m[7];
        #pragma unroll
        for (int i = 0; i < 7; i++) {
            int j = i * 64 + lane;
            if (j < 400) { p[i] *= inv; m[i] = p[i]; }
            else m[i] = -1e30f;
        }
        for (int it = 0; it < 15; ++it) {
            float lm = m[0];
            #pragma unroll
            for (int i = 1; i < 7; i++) lm = fmaxf(lm, m[i]);
            float gm = lm;
            #pragma unroll
            for (int o = 32; o > 0; o >>= 1) gm = fmaxf(gm, __shfl_xor(gm, o, 64));
            unsigned long long msk = __ballot(lm == gm);
            int first = (int)(__ffsll((long long)msk)) - 1;
            if (lane == first) {
                #pragma unroll
                for (int i = 0; i < 7; i++) {
                    if (m[i] == gm) { m[i] = -1e30f; break; }
                }
            }
        }
        float kth = m[0];
        #pragma unroll
        for (int i = 1; i < 7; i++) kth = fmaxf(kth, m[i]);
        #pragma unroll
        for (int o = 32; o > 0; o >>= 1) kth = fmaxf(kth, __shfl_xor(kth, o, 64));
        int base = 0;
        #pragma unroll
        for (int i = 0; i < 7; i++) {
            int j = i * 64 + lane;
            bool pred = (j < 400) && (p[i] >= kth);
            unsigned long long msk = __ballot(pred);
            int pre = __popcll(msk & ((lane == 63) ? 0x7fffffffffffffffull : ((1ull << lane) - 1)));
            if (pred) {
                int pos = base + pre;
                if (pos < 64) {
                    idxs[n * 64 + pos] = j;
                    logv[n * 64 + pos] = logf(fmaxf(p[i], 1e-12f));
                }
            }
            base += __popcll(msk);
        }
        if (lane == 0) cnt[n] = base < 64 ? base : 64;
    } else {
        // ---- TCN layer 0: one WAVE per node, 4 channels per lane, no barriers
        int lane = tid & 63;
        int node = (bid - 4581) * 4 + (tid >> 6);
        float xs[14];
        #pragma unroll
        for (int t = 0; t < 7; t++) {
            xs[t * 2]     = x[(size_t)(node * 12 + 5 + t) * 2];
            xs[t * 2 + 1] = x[(size_t)(node * 12 + 5 + t) * 2 + 1];
        }
        float wg[4][6], wf[4][6], wsv[4][6], bgv[4], bfv[4], bsv[4], gln[4], bln[4];
        #pragma unroll
        for (int cc = 0; cc < 4; cc++) {
            int o = lane * 4 + cc;
            #pragma unroll
            for (int i = 0; i < 6; i++) {
                wg[cc][i] = wg0[o * 6 + i];
                wf[cc][i] = wf0[o * 6 + i];
                wsv[cc][i] = ws0[o * 6 + i];
            }
            bgv[cc] = bg0[o]; bfv[cc] = bf0[o]; bsv[cc] = bs0[o];
            gln[cc] = lg0[o]; bln[cc] = lb0[o];
        }
        #pragma unroll
        for (int tt = 0; tt < 3; tt++) {
            int tb = 2 * tt;  // xs index of t-2 for t=7+2tt (t-2-5 = 2tt)
            float y[4];
            float s1 = 0.f, s2 = 0.f;
            #pragma unroll
            for (int cc = 0; cc < 4; cc++) {
                float g = bgv[cc], f = bfv[cc], s = bsv[cc];
                #pragma unroll
                for (int k = 0; k < 3; k++) {
                    #pragma unroll
                    for (int c = 0; c < 2; c++) {
                        float xv = xs[(tb + k) * 2 + c];
                        g += wg[cc][c * 3 + k] * xv;
                        f += wf[cc][c * 3 + k] * xv;
                        s += wsv[cc][c * 3 + k] * xv;
                    }
                }
                float gate = 1.f / (1.f + expf(-g));
                y[cc] = gate * f + (1.f - gate) * s;
                s1 += y[cc];
                s2 += y[cc] * y[cc];
            }
            #pragma unroll
            for (int o = 32; o > 0; o >>= 1) {
                s1 += __shfl_xor(s1, o, 64);
                s2 += __shfl_xor(s2, o, 64);
            }
            float mean = s1 * (1.f / 256.f);
            float var = s2 * (1.f / 256.f) - mean * mean;
            float rstd = rsqrtf(var + 1e-5f);
            unsigned short h4[4];
            #pragma unroll
            for (int cc = 0; cc < 4; cc++) {
                float v = (y[cc] - mean) * rstd * gln[cc] + bln[cc];
                h4[cc] = f2h(fmaxf(v, 0.f));
            }
            unsigned long long pack = (unsigned long long)h4[0] | ((unsigned long long)h4[1] << 16)
                                    | ((unsigned long long)h4[2] << 32) | ((unsigned long long)h4[3] << 48);
            *(unsigned long long*)&Xh[(size_t)node * 768 + tt * 256 + lane * 4] = pack;
        }
    }
}

// ---------------- fp16 MFMA GEMM, 64x64 tile, BK=32, 3-stage counted-vmcnt pipeline ----------------
template<int K, int LDC, int GX>
__global__ __launch_bounds__(256, 6) void gemm_f16(
    const unsigned short* __restrict__ A,
    const unsigned short* __restrict__ BT,
    unsigned short* __restrict__ C) {
    __shared__ __align__(16) unsigned short lA[3][64 * 32];    // 12KB
    __shared__ __align__(16) unsigned short lB[3][64 * 32];    // 12KB -> 24KB total
    int tid = threadIdx.x;
    int lane = tid & 63;
    int w = tid >> 6;
    int wm = w >> 1, wn = w & 1;
    int r = lane & 15, g4 = lane >> 4;

    // bijective XCD swizzle (m204); NWG % 8 == 0 for all our grids
    constexpr int NWG = GX * 100;
    constexpr int Q = NWG / 8, R = NWG % 8;
    int flat = blockIdx.y * GX + blockIdx.x;
    int xcd = flat & 7, idx = flat >> 3;
    int nf = (xcd < R ? xcd * (Q + 1) : R * (Q + 1) + (xcd - R) * Q) + idx;
    int col0 = (nf % GX) * 64;
    int row0 = (nf / GX) * 64;

    f32x4 acc[2][2] = {};

    // staging: linear LDS dest; global source k-slot pre-swizzled (rule #21)
    int rS = tid >> 2;                  // staged row 0..63
    int slot = tid & 3;                 // 16B slot within row
    int tk = (slot ^ (rS & 3)) * 8;     // swizzled k offset (halves)

#define STAGE(sel, kk) do { \
    GLOAD16(A + (size_t)(row0 + rS) * K + (kk) + tk, &lA[sel][tid * 8]); \
    GLOAD16(BT + (size_t)(col0 + rS) * K + (kk) + tk, &lB[sel][tid * 8]); \
} while (0)

    int sw = (g4 ^ (r & 3)) << 3;       // swizzled read slot (halves)

#define COMPUTE(cur) do { \
    half8 a_[2], b_[2]; \
    _Pragma("unroll") \
    for (int mi = 0; mi < 2; ++mi) \
        a_[mi] = *(const half8*)&lA[cur][(wm * 32 + mi * 16 + r) * 32 + sw]; \
    _Pragma("unroll") \
    for (int ni = 0; ni < 2; ++ni) \
        b_[ni] = *(const half8*)&lB[cur][(wn * 32 + ni * 16 + r) * 32 + sw]; \
    _Pragma("unroll") \
    for (int mi = 0; mi < 2; ++mi) \
        _Pragma("unroll") \
        for (int ni = 0; ni < 2; ++ni) \
            acc[mi][ni] = __builtin_amdgcn_mfma_f32_16x16x32_f16(a_[mi], b_[ni], acc[mi][ni], 0, 0, 0); \
} while (0)

    constexpr int NT = K >> 5;
    STAGE(0, 0);
    STAGE(1, 32);
    for (int t = 0; t < NT - 1; ++t) {
        asm volatile("s_waitcnt vmcnt(2)" ::: "memory");
        __builtin_amdgcn_s_barrier();
        if (t + 2 < NT) STAGE((t + 2) % 3, (t + 2) * 32);
        COMPUTE(t % 3);
    }
    asm volatile("s_waitcnt vmcnt(0)" ::: "memory");
    __builtin_amdgcn_s_barrier();
    COMPUTE((NT - 1) % 3);
#undef STAGE
#undef COMPUTE

    #pragma unroll
    for (int mi = 0; mi < 2; ++mi) {
        #pragma unroll
        for (int ni = 0; ni < 2; ++ni) {
            int rowb = row0 + wm * 32 + mi * 16 + g4 * 4;
            int colb = col0 + wn * 32 + ni * 16 + r;
            #pragma unroll
            for (int j = 0; j < 4; ++j)
                C[(size_t)(rowb + j) * LDC + colb] = f2h(acc[mi][ni][j]);
        }
    }
}

// ---------------- layer-1 epilogue (fp16 in) -> HLh ----------------
__global__ __launch_bounds__(256) void epi1_kernel(
    const unsigned short* __restrict__ Y1, const float* __restrict__ x,
    const float* __restrict__ bg1, const float* __restrict__ bf1, const float* __restrict__ bs1,
    const float* __restrict__ lg, const float* __restrict__ lb,
    const float* __restrict__ wsk, const float* __restrict__ bsk,
    unsigned short* __restrict__ HLh) {
    int node = blockIdx.x, o = threadIdx.x;
    __shared__ float red[8];
    size_t base = (size_t)node * 768;
    float g = h2f(Y1[base + o]) + bg1[o];
    float f = h2f(Y1[base + 256 + o]) + bf1[o];
    float s = h2f(Y1[base + 512 + o]) + bs1[o];
    float gate = 1.f / (1.f + expf(-g));
    float y = gate * f + (1.f - gate) * s;
    float a = y, bb = y * y;
    #pragma unroll
    for (int off = 32; off > 0; off >>= 1) { a += __shfl_xor(a, off, 64); bb += __shfl_xor(bb, off, 64); }
    int w = o >> 6, l = o & 63;
    if (l == 0) { red[w] = a; red[4 + w] = bb; }
    __syncthreads();
    float sum = red[0] + red[1] + red[2] + red[3];
    float sq = red[4] + red[5] + red[6] + red[7];
    float mean = sum * (1.f / 256.f);
    float var = sq * (1.f / 256.f) - mean * mean;
    float v = (y - mean) * rsqrtf(var + 1e-5f) * lg[o] + lb[o];
    v = fmaxf(v, 0.f);
    float x0 = x[(size_t)(node * 12 + 11) * 2];
    float x1 = x[(size_t)(node * 12 + 11) * 2 + 1];
    float res = x0 * wsk[o] + x1 * wsk[256 + o] + bsk[o];
    HLh[(size_t)node * 256 + o] = f2h(v + res);
}

// ---------------- fused GAT: one block per node, 1 barrier, short2 gathers ----------------
__global__ __launch_bounds__(256) void gat_kernel(
    const unsigned short* __restrict__ Y2, const float* __restrict__ ef,
    const int* __restrict__ fei, const float* __restrict__ AeS,
    const int* __restrict__ cnt, const int* __restrict__ idxs, const float* __restrict__ logv,
    unsigned short* __restrict__ Uh) {
    int node = blockIdx.x;
    int b = node / 400, n = node % 400;
    int tid = threadIdx.x;
    __shared__ int snd[9];
    __shared__ float alf[9][8];
    __shared__ float invdf[8];
    __shared__ int jidx[64];
    __shared__ float sca[64][8];
    __shared__ float alb[64][8];
    __shared__ float invda[8];
    __shared__ float svf[9][8];
    int c = cnt[n];

    if (tid < 64) {
        // ======== WAVE 0: fixed scores + softmax (wave-synchronous) ========
        int lane = tid;
        if (lane < 9) snd[lane] = fei[LL + n * 9 + lane];
        // scores: e = j*8+h, 72 total
        for (int e = lane; e < 72; e += 64) {
            int j = e >> 3, h = e & 7;
            int l = n * 9 + j;
            float e0 = ef[((size_t)b * LL + l) * 2];
            float e1 = ef[((size_t)b * LL + l) * 2 + 1];
            float ae = e0 * AeS[h] + e1 * AeS[8 + h];
            float aq = h2f(Y2[(size_t)node * 640 + 512 + h]);
            float ak = h2f(Y2[((size_t)(b * 400 + snd[j])) * 640 + 520 + h]);
            float s = aq + ak + ae;
            svf[j][h] = s > 0.f ? s : 0.2f * s;
        }
        // softmax by lanes 0-7 (reads svf written by this wave)
        if (lane < 8) {
            int h = lane;
            float mx = -1e30f;
            #pragma unroll
            for (int j = 0; j < 9; j++) mx = fmaxf(mx, svf[j][h]);
            float den = 0.f;
            #pragma unroll
            for (int j = 0; j < 9; j++) { float e = expf(svf[j][h] - mx); alf[j][h] = e; den += e; }
            invdf[h] = 1.f / fmaxf(den, 1e-12f);
        }
    } else if (tid < 128) {
        // ======== WAVE 1: adaptive scores + wave-local softmax ========
        int lane = tid - 64;
        if (lane < c) jidx[lane] = idxs[n * 64 + lane];
        float jl = (lane < c) ? logv[n * 64 + lane] : 0.f;
        // broadcast jlog via LDS? store scores directly with jlog folded:
        // first everyone needs jidx; wave-sync ok (written above by this wave)
        for (int e = lane; e < c * 8; e += 64) {
            int j = e >> 3, h = e & 7;
            float aq = h2f(Y2[(size_t)node * 640 + 528 + h]);
            float ak = h2f(Y2[((size_t)(b * 400 + jidx[j])) * 640 + 536 + h]);
            float s = aq + ak;
            s = s > 0.f ? s : 0.2f * s;
            // jlog[j] is in lane j's register; read via shuffle
            sca[j][h] = s + __shfl(jl, j, 64);
        }
        // wave-local softmax: h = lane>>3, grp = lane&7
        int h = lane >> 3, grp = lane & 7;
        float mx = -1e30f;
        for (int j = grp; j < c; j += 8) mx = fmaxf(mx, sca[j][h]);
        #pragma unroll
        for (int o = 1; o < 8; o <<= 1) mx = fmaxf(mx, __shfl_xor(mx, o, 64));
        float s = 0.f;
        for (int j = grp; j < c; j += 8) { float e = expf(sca[j][h] - mx); alb[j][h] = e; s += e; }
        #pragma unroll
        for (int o = 1; o < 8; o <<= 1) s += __shfl_xor(s, o, 64);
        if (grp == 0) invda[h] = 1.f / s;
    }
    __syncthreads();

    if (tid < 128) {
        // fixed aggregation: 2 channels/thread, short2 gathers
        int ch = tid * 2;
        int h = ch >> 5;
        float a0 = 0.f, a1 = 0.f;
        #pragma unroll
        for (int j = 0; j < 9; j++) {
            unsigned v = *(const unsigned*)&Y2[((size_t)(b * 400 + snd[j])) * 640 + ch];
            float al = alf[j][h];
            a0 += al * h2f((unsigned short)(v & 0xffff));
            a1 += al * h2f((unsigned short)(v >> 16));
        }
        float iv = invdf[h];
        a0 *= iv; a1 *= iv;
        a0 = a0 > 0.f ? a0 : (expf(a0) - 1.f);
        a1 = a1 > 0.f ? a1 : (expf(a1) - 1.f);
        unsigned o = (unsigned)f2h(a0) | ((unsigned)f2h(a1) << 16);
        *(unsigned*)&Uh[(size_t)node * 512 + ch] = o;
    } else {
        // adaptive aggregation
        int ch = (tid - 128) * 2;
        int h = ch >> 5;
        float a0 = 0.f, a1 = 0.f;
        for (int j = 0; j < c; j++) {
            unsigned v = *(const unsigned*)&Y2[((size_t)(b * 400 + jidx[j])) * 640 + 256 + ch];
            float al = alb[j][h];
            a0 += al * h2f((unsigned short)(v & 0xffff));
            a1 += al * h2f((unsigned short)(v >> 16));
        }
        float iv = invda[h];
        a0 *= iv; a1 *= iv;
        a0 = a0 > 0.f ? a0 : (expf(a0) - 1.f);
        a1 = a1 > 0.f ? a1 : (expf(a1) - 1.f);
        unsigned o = (unsigned)f2h(a0) | ((unsigned)f2h(a1) << 16);
        *(unsigned*)&Uh[(size_t)node * 512 + 256 + ch] = o;
    }
}

// ---------------- final fuse + output projection (fp16 in) ----------------
__global__ __launch_bounds__(256) void final_kernel(
    const unsigned short* __restrict__ Y3,
    const float* __restrict__ fb1, const float* __restrict__ fb2, const float* __restrict__ fb3,
    const float* __restrict__ Wo, const float* __restrict__ bo,
    float* __restrict__ out) {
    int node = blockIdx.x, o = threadIdx.x;
    __shared__ float red[12];
    size_t base = (size_t)node * 768;
    float g = 1.f / (1.f + expf(-(h2f(Y3[base + o]) + fb1[o])));
    float a2 = h2f(Y3[base + 256 + o]) + fb2[o];
    float a3 = h2f(Y3[base + 512 + o]) + fb3[o];
    float fused = tanhf(g * a2 + (1.f - g) * a3);
    float v0 = fused * Wo[o * 3 + 0];
    float v1 = fused * Wo[o * 3 + 1];
    float v2 = fused * Wo[o * 3 + 2];
    #pragma unroll
    for (int off = 32; off > 0; off >>= 1) {
        v0 += __shfl_xor(v0, off, 64);
        v1 += __shfl_xor(v1, off, 64);
        v2 += __shfl_xor(v2, off, 64);
    }
    int w = o >> 6, l = o & 63;
    if (l == 0) { red[w] = v0; red[4 + w] = v1; red[8 + w] = v2; }
    __syncthreads();
    if (o < 3) {
        float s = red[o * 4] + red[o * 4 + 1] + red[o * 4 + 2] + red[o * 4 + 3];
        out[(size_t)node * 3 + o] = s + bo[o];
    }
}

// ---------------- launcher ----------------
extern "C" void kernel_launch(void* const* d_in, const int* in_sizes, int n_in,
                              void* d_out, int out_size, void* d_ws, size_t ws_size,
                              hipStream_t stream) {
    const float* x   = (const float*)d_in[0];
    const float* ef  = (const float*)d_in[1];
    const int*   fei = (const int*)d_in[2];
    const float* wg0 = (const float*)d_in[3];
    const float* bg0 = (const float*)d_in[4];
    const float* wf0 = (const float*)d_in[5];
    const float* bf0 = (const float*)d_in[6];
    const float* ws0 = (const float*)d_in[7];
    const float* bs0 = (const float*)d_in[8];
    const float* ln0g = (const float*)d_in[9];
    const float* ln0b = (const float*)d_in[10];
    const float* wg1 = (const float*)d_in[11];
    const float* bg1 = (const float*)d_in[12];
    const float* wf1 = (const float*)d_in[13];
    const float* bf1 = (const float*)d_in[14];
    const float* ws1 = (const float*)d_in[15];
    const float* bs1 = (const float*)d_in[16];
    const float* ln1g = (const float*)d_in[17];
    const float* ln1b = (const float*)d_in[18];
    const float* wsk = (const float*)d_in[19];
    const float* bsk = (const float*)d_in[20];
    const float* sWq = (const float*)d_in[21];
    const float* sWk = (const float*)d_in[22];
    const float* sWv = (const float*)d_in[23];
    const float* sWe = (const float*)d_in[24];
    const float* saq = (const float*)d_in[25];
    const float* sak = (const float*)d_in[26];
    const float* sae = (const float*)d_in[27];
    const float* dWq = (const float*)d_in[28];
    const float* dWk = (const float*)d_in[29];
    const float* dWv = (const float*)d_in[30];
    const float* daq = (const float*)d_in[31];
    const float* dak = (const float*)d_in[32];
    const float* E1  = (const float*)d_in[33];
    const float* E2  = (const float*)d_in[34];
    const float* fW1 = (const float*)d_in[35];
    const float* fb1 = (const float*)d_in[36];
    const float* fW2 = (const float*)d_in[37];
    const float* fb2 = (const float*)d_in[38];
    const float* fW3 = (const float*)d_in[39];
    const float* fb3 = (const float*)d_in[40];
    const float* Wo  = (const float*)d_in[41];
    const float* bo  = (const float*)d_in[42];
    float* out = (float*)d_out;

    char* b = (char*)d_ws;
    unsigned short* Xh  = (unsigned short*)(b + 0);          // 9,830,400
    unsigned short* Yh  = (unsigned short*)(b + 9830400);    // 9,830,400 (Y1/Y2/Y3 fp16, reused)
    unsigned short* HLh = (unsigned short*)(b + 19660800);   // 3,276,800
    unsigned short* Uh  = (unsigned short*)(b + 22937600);   // 6,553,600
    unsigned short* W1h = (unsigned short*)(b + 29491200);   // 1,179,648
    unsigned short* W2h = (unsigned short*)(b + 30670848);   // 327,680
    unsigned short* W3h = (unsigned short*)(b + 30998528);   // 786,432
    float*          AES = (float*)(b + 31784960);            // 64 (+pad)
    float*          LOGV= (float*)(b + 31785216);            // 102,400
    int*            CNT = (int*)(b + 31887616);              // 1,600
    int*            IDX = (int*)(b + 31889216);              // 102,400

    // all input-only work in ONE launch
    prep_kernel<<<6181, 256, 0, stream>>>(
        wg1, wf1, ws1,
        sWv, dWv, sWq, saq, sWk, sak, dWq, daq, dWk, dak,
        fW1, fW2, fW3, sWe, sae, E1, E2,
        x, wg0, bg0, wf0, bf0, ws0, bs0, ln0g, ln0b,
        W1h, W2h, W3h, AES,
        CNT, IDX, LOGV, Xh);

    // G1: Y1 = X @ W1  (M=6400, N=768, K=768) -> fp16
    gemm_f16<768, 768, 12><<<dim3(12, 100), 256, 0, stream>>>(Xh, W1h, Yh);

    epi1_kernel<<<NODES, 256, 0, stream>>>(Yh, x, bg1, bf1, bs1, ln1g, ln1b, wsk, bsk, HLh);

    // G2: Y2 = HL @ W2 (M=6400, N=640, K=256) -> fp16 (reuses Yh after epi1)
    gemm_f16<256, 640, 10><<<dim3(10, 100), 256, 0, stream>>>(HLh, W2h, Yh);

    // fused attention stages -> U (one block per node)
    gat_kernel<<<NODES, 256, 0, stream>>>(Yh, ef, fei, AES, CNT, IDX, LOGV, Uh);

    // G3: Y3 = U @ W3 (M=6400, N=768, K=512) -> fp16 (reuses Yh after gat)
    gemm_f16<512, 768, 12><<<dim3(12, 100), 256, 0, stream>>>(Uh, W3h, Yh);

    final_kernel<<<NODES, 256, 0, stream>>>(Yh, fb1, fb2, fb3, Wo, bo, out);
}

// Round 10
// 99.088 us; speedup vs baseline: 1.2462x; 1.0105x over previous
//
#include <hip/hip_runtime.h>
#include <math.h>

// Problem constants
#define LL 3600
#define NODES 6400

typedef __attribute__((ext_vector_type(8))) _Float16 half8;
typedef __attribute__((ext_vector_type(4))) float f32x4;

// ---------------- fp16 helpers ----------------
__device__ __forceinline__ unsigned short f2h(float f) {
    union { _Float16 h; unsigned short u; } cv;
    cv.h = (_Float16)f;
    return cv.u;
}
__device__ __forceinline__ float h2f(unsigned short u) {
    union { unsigned short u; _Float16 h; } cv;
    cv.u = u;
    return (float)cv.h;
}

#define GLOAD16(gp, lp) __builtin_amdgcn_global_load_lds( \
    (const __attribute__((address_space(1))) unsigned int*)(const void*)(gp), \
    (__attribute__((address_space(3))) unsigned int*)(void*)(lp), 16, 0, 0)

// ================= MEGA PREP KERNEL =================
// blocks [0,2304): W1T | [2304,2944): W2T | [2944,4480): W3T
// [4480]: AeS | [4481,4581): adj | [4581,6181): tcn0 | [6181,6256): out bias-init
__global__ __launch_bounds__(256) void prep_kernel(
    const float* __restrict__ wg1, const float* __restrict__ wf1, const float* __restrict__ ws1,
    const float* __restrict__ sWv, const float* __restrict__ dWv,
    const float* __restrict__ sWq, const float* __restrict__ saq,
    const float* __restrict__ sWk, const float* __restrict__ sak,
    const float* __restrict__ dWq, const float* __restrict__ daq,
    const float* __restrict__ dWk, const float* __restrict__ dak,
    const float* __restrict__ fW1, const float* __restrict__ fW2, const float* __restrict__ fW3,
    const float* __restrict__ sWe, const float* __restrict__ sae,
    const float* __restrict__ E1, const float* __restrict__ E2,
    const float* __restrict__ x,
    const float* __restrict__ wg0, const float* __restrict__ bg0,
    const float* __restrict__ wf0, const float* __restrict__ bf0,
    const float* __restrict__ ws0, const float* __restrict__ bs0,
    const float* __restrict__ lg0, const float* __restrict__ lb0,
    const float* __restrict__ bo,
    unsigned short* __restrict__ W1h,
    unsigned short* __restrict__ W2h,
    unsigned short* __restrict__ W3h,
    float* __restrict__ AeS,
    int* __restrict__ cnt, int* __restrict__ idxs, float* __restrict__ logv,
    unsigned short* __restrict__ Xh,
    float* __restrict__ out) {
    int bid = blockIdx.x;
    int tid = threadIdx.x;

    if (bid < 2304) {
        // ---- W1T[n][k]: n = which*256+o, k = tt*256+i; val = w1[o][i][tt]
        int idx = bid * 256 + tid;
        int n = idx / 768, k = idx % 768;
        int which = n >> 8, o = n & 255;
        int tt = k >> 8, i = k & 255;
        const float* w = which == 0 ? wg1 : (which == 1 ? wf1 : ws1);
        W1h[idx] = f2h(w[(o * 256 + i) * 3 + tt]);
    } else if (bid < 2944) {
        // ---- W2T[n][k], n in [0,640), k in [0,256)
        int idx = (bid - 2304) * 256 + tid;
        int n = idx / 256, k = idx % 256;
        float v = 0.f;
        if (n < 256) v = sWv[k * 256 + n];
        else if (n < 512) v = dWv[k * 256 + (n - 256)];
        else if (n < 544) {
            int j = n - 512, g = j >> 3, h = j & 7;
            const float* Wm = g == 0 ? sWq : (g == 1 ? sWk : (g == 2 ? dWq : dWk));
            const float* am = g == 0 ? saq : (g == 1 ? sak : (g == 2 ? daq : dak));
            float s = 0.f;
            for (int d = 0; d < 32; d++) s += Wm[k * 256 + h * 32 + d] * am[h * 32 + d];
            v = s;
        }
        W2h[idx] = f2h(v);
    } else if (bid < 4480) {
        // ---- W3T[n][k], n in [0,768), k in [0,512)
        int idx = (bid - 2944) * 256 + tid;
        int n = idx / 512, k = idx % 512;
        float v = 0.f;
        if (k < 256) {
            if (n < 256) v = fW1[k * 256 + n];
            else if (n < 512) v = fW2[k * 256 + (n - 256)];
        } else {
            int c = k - 256;
            if (n < 256) v = fW1[c * 256 + n];
            else if (n >= 512) v = fW3[c * 256 + (n - 512)];
        }
        W3h[idx] = f2h(v);
    } else if (bid == 4480) {
        if (tid < 16) {
            int cc = tid / 8, h = tid % 8;
            float s = 0.f;
            for (int d = 0; d < 32; d++) s += sWe[cc * 256 + h * 32 + d] * sae[h * 32 + d];
            AeS[tid] = s;
        }
    } else if (bid < 4581) {
        // ---- adjacency: one wave per row
        int n = ((bid - 4481) * 256 + tid) >> 6;
        int lane = tid & 63;
        if (n >= 400) return;
        float e1[10];
        #pragma unroll
        for (int k = 0; k < 10; k++) e1[k] = E1[n * 10 + k];
        float p[7];
        #pragma unroll
        for (int i = 0; i < 7; i++) {
            int j = i * 64 + lane;
            if (j < 400) {
                float s = 0.f;
                #pragma unroll
                for (int k = 0; k < 10; k++) s += e1[k] * E2[j * 10 + k];
                p[i] = fmaxf(s, 0.f);
            } else p[i] = -1e30f;
        }
        float mx = -1e30f;
        #pragma unroll
        for (int i = 0; i < 7; i++) mx = fmaxf(mx, p[i]);
        #pragma unroll
        for (int o = 32; o > 0; o >>= 1) mx = fmaxf(mx, __shfl_xor(mx, o, 64));
        float sum = 0.f;
        #pragma unroll
        for (int i = 0; i < 7; i++) {
            int j = i * 64 + lane;
            if (j < 400) { p[i] = expf(p[i] - mx); sum += p[i]; }
        }
        #pragma unroll
        for (int o = 32; o > 0; o >>= 1) sum += __shfl_xor(sum, o, 64);
        float inv = 1.f / sum;
        float m[7];
        #pragma unroll
        for (int i = 0; i < 7; i++) {
            int j = i * 64 + lane;
            if (j < 400) { p[i] *= inv; m[i] = p[i]; }
            else m[i] = -1e30f;
        }
        for (int it = 0; it < 15; ++it) {
            float lm = m[0];
            #pragma unroll
            for (int i = 1; i < 7; i++) lm = fmaxf(lm, m[i]);
            float gm = lm;
            #pragma unroll
            for (int o = 32; o > 0; o >>= 1) gm = fmaxf(gm, __shfl_xor(gm, o, 64));
            unsigned long long msk = __ballot(lm == gm);
            int first = (int)(__ffsll((long long)msk)) - 1;
            if (lane == first) {
                #pragma unroll
                for (int i = 0; i < 7; i++) {
                    if (m[i] == gm) { m[i] = -1e30f; break; }
                }
            }
        }
        float kth = m[0];
        #pragma unroll
        for (int i = 1; i < 7; i++) kth = fmaxf(kth, m[i]);
        #pragma unroll
        for (int o = 32; o > 0; o >>= 1) kth = fmaxf(kth, __shfl_xor(kth, o, 64));
        int base = 0;
        #pragma unroll
        for (int i = 0; i < 7; i++) {
            int j = i * 64 + lane;
            bool pred = (j < 400) && (p[i] >= kth);
            unsigned long long msk = __ballot(pred);
            int pre = __popcll(msk & ((lane == 63) ? 0x7fffffffffffffffull : ((1ull << lane) - 1)));
            if (pred) {
                int pos = base + pre;
                if (pos < 64) {
                    idxs[n * 64 + pos] = j;
                    logv[n * 64 + pos] = logf(fmaxf(p[i], 1e-12f));
                }
            }
            base += __popcll(msk);
        }
        if (lane == 0) cnt[n] = base < 64 ? base : 64;
    } else if (bid < 6181) {
        // ---- TCN layer 0: one WAVE per node, 4 channels per lane, no barriers
        int lane = tid & 63;
        int node = (bid - 4581) * 4 + (tid >> 6);
        float xs[14];
        #pragma unroll
        for (int t = 0; t < 7; t++) {
            xs[t * 2]     = x[(size_t)(node * 12 + 5 + t) * 2];
            xs[t * 2 + 1] = x[(size_t)(node * 12 + 5 + t) * 2 + 1];
        }
        float wg[4][6], wf[4][6], wsv[4][6], bgv[4], bfv[4], bsv[4], gln[4], bln[4];
        #pragma unroll
        for (int cc = 0; cc < 4; cc++) {
            int o = lane * 4 + cc;
            #pragma unroll
            for (int i = 0; i < 6; i++) {
                wg[cc][i] = wg0[o * 6 + i];
                wf[cc][i] = wf0[o * 6 + i];
                wsv[cc][i] = ws0[o * 6 + i];
            }
            bgv[cc] = bg0[o]; bfv[cc] = bf0[o]; bsv[cc] = bs0[o];
            gln[cc] = lg0[o]; bln[cc] = lb0[o];
        }
        #pragma unroll
        for (int tt = 0; tt < 3; tt++) {
            int tb = 2 * tt;
            float y[4];
            float s1 = 0.f, s2 = 0.f;
            #pragma unroll
            for (int cc = 0; cc < 4; cc++) {
                float g = bgv[cc], f = bfv[cc], s = bsv[cc];
                #pragma unroll
                for (int k = 0; k < 3; k++) {
                    #pragma unroll
                    for (int c = 0; c < 2; c++) {
                        float xv = xs[(tb + k) * 2 + c];
                        g += wg[cc][c * 3 + k] * xv;
                        f += wf[cc][c * 3 + k] * xv;
                        s += wsv[cc][c * 3 + k] * xv;
                    }
                }
                float gate = 1.f / (1.f + expf(-g));
                y[cc] = gate * f + (1.f - gate) * s;
                s1 += y[cc];
                s2 += y[cc] * y[cc];
            }
            #pragma unroll
            for (int o = 32; o > 0; o >>= 1) {
                s1 += __shfl_xor(s1, o, 64);
                s2 += __shfl_xor(s2, o, 64);
            }
            float mean = s1 * (1.f / 256.f);
            float var = s2 * (1.f / 256.f) - mean * mean;
            float rstd = rsqrtf(var + 1e-5f);
            unsigned short h4[4];
            #pragma unroll
            for (int cc = 0; cc < 4; cc++) {
                float v = (y[cc] - mean) * rstd * gln[cc] + bln[cc];
                h4[cc] = f2h(fmaxf(v, 0.f));
            }
            unsigned long long pack = (unsigned long long)h4[0] | ((unsigned long long)h4[1] << 16)
                                    | ((unsigned long long)h4[2] << 32) | ((unsigned long long)h4[3] << 48);
            *(unsigned long long*)&Xh[(size_t)node * 768 + tt * 256 + lane * 4] = pack;
        }
    } else {
        // ---- out bias-init: out[n*3+p] = bo[p]
        int idx = (bid - 6181) * 256 + tid;
        if (idx < NODES * 3) out[idx] = bo[idx % 3];
    }
}

// ---------------- fp16 MFMA GEMM, 64x64 tile, BK=32, 3-stage counted-vmcnt pipeline ----------------
template<int K, int LDC, int GX>
__global__ __launch_bounds__(256, 6) void gemm_f16(
    const unsigned short* __restrict__ A,
    const unsigned short* __restrict__ BT,
    unsigned short* __restrict__ C) {
    __shared__ __align__(16) unsigned short lA[3][64 * 32];    // 12KB
    __shared__ __align__(16) unsigned short lB[3][64 * 32];    // 12KB -> 24KB total
    int tid = threadIdx.x;
    int lane = tid & 63;
    int w = tid >> 6;
    int wm = w >> 1, wn = w & 1;
    int r = lane & 15, g4 = lane >> 4;

    // bijective XCD swizzle (m204)
    constexpr int NWG = GX * 100;
    constexpr int Q = NWG / 8, R = NWG % 8;
    int flat = blockIdx.y * GX + blockIdx.x;
    int xcd = flat & 7, idx = flat >> 3;
    int nf = (xcd < R ? xcd * (Q + 1) : R * (Q + 1) + (xcd - R) * Q) + idx;
    int col0 = (nf % GX) * 64;
    int row0 = (nf / GX) * 64;

    f32x4 acc[2][2] = {};

    int rS = tid >> 2;                  // staged row 0..63
    int slot = tid & 3;                 // 16B slot within row
    int tk = (slot ^ (rS & 3)) * 8;     // swizzled k offset (halves)

#define STAGE(sel, kk) do { \
    GLOAD16(A + (size_t)(row0 + rS) * K + (kk) + tk, &lA[sel][tid * 8]); \
    GLOAD16(BT + (size_t)(col0 + rS) * K + (kk) + tk, &lB[sel][tid * 8]); \
} while (0)

    int sw = (g4 ^ (r & 3)) << 3;       // swizzled read slot (halves)

#define COMPUTE(cur) do { \
    half8 a_[2], b_[2]; \
    _Pragma("unroll") \
    for (int mi = 0; mi < 2; ++mi) \
        a_[mi] = *(const half8*)&lA[cur][(wm * 32 + mi * 16 + r) * 32 + sw]; \
    _Pragma("unroll") \
    for (int ni = 0; ni < 2; ++ni) \
        b_[ni] = *(const half8*)&lB[cur][(wn * 32 + ni * 16 + r) * 32 + sw]; \
    _Pragma("unroll") \
    for (int mi = 0; mi < 2; ++mi) \
        _Pragma("unroll") \
        for (int ni = 0; ni < 2; ++ni) \
            acc[mi][ni] = __builtin_amdgcn_mfma_f32_16x16x32_f16(a_[mi], b_[ni], acc[mi][ni], 0, 0, 0); \
} while (0)

    constexpr int NT = K >> 5;
    STAGE(0, 0);
    STAGE(1, 32);
    for (int t = 0; t < NT - 1; ++t) {
        asm volatile("s_waitcnt vmcnt(2)" ::: "memory");
        __builtin_amdgcn_s_barrier();
        if (t + 2 < NT) STAGE((t + 2) % 3, (t + 2) * 32);
        COMPUTE(t % 3);
    }
    asm volatile("s_waitcnt vmcnt(0)" ::: "memory");
    __builtin_amdgcn_s_barrier();
    COMPUTE((NT - 1) % 3);
#undef STAGE
#undef COMPUTE

    #pragma unroll
    for (int mi = 0; mi < 2; ++mi) {
        #pragma unroll
        for (int ni = 0; ni < 2; ++ni) {
            int rowb = row0 + wm * 32 + mi * 16 + g4 * 4;
            int colb = col0 + wn * 32 + ni * 16 + r;
            #pragma unroll
            for (int j = 0; j < 4; ++j)
                C[(size_t)(rowb + j) * LDC + colb] = f2h(acc[mi][ni][j]);
        }
    }
}

// ---------------- G3 with fused tail: U @ W3 -> fused -> @Wo -> atomic out ----------------
// Block: 64 rows x (64 cols x 3 chunks). Grid (4, 100). K=512, BK=32.
__global__ __launch_bounds__(256, 3) void gemm3_fused(
    const unsigned short* __restrict__ A,      // Uh (6400 x 512)
    const unsigned short* __restrict__ BT,     // W3h (768 x 512)
    const float* __restrict__ fb1, const float* __restrict__ fb2, const float* __restrict__ fb3,
    const float* __restrict__ Wo,
    float* __restrict__ out) {
    __shared__ __align__(16) unsigned short lA[3][64 * 32];       // 12KB
    __shared__ __align__(16) unsigned short lB[3][3][64 * 32];    // 36KB -> 48KB
    int tid = threadIdx.x;
    int lane = tid & 63;
    int w = tid >> 6;
    int wm = w >> 1, wn = w & 1;
    int r = lane & 15, g4 = lane >> 4;

    // bijective XCD swizzle: NWG=400, R=0
    constexpr int NWG = 400;
    constexpr int Q = NWG / 8;
    int flat = blockIdx.y * 4 + blockIdx.x;
    int xcd = flat & 7, idx = flat >> 3;
    int nf = xcd * Q + idx;
    int c0 = (nf % 4) * 64;            // channel-slice base in [0,256)
    int row0 = (nf / 4) * 64;

    f32x4 acc[3][2][2] = {};

    int rS = tid >> 2;
    int slot = tid & 3;
    int tk = (slot ^ (rS & 3)) * 8;

#define STAGE3(sel, kk) do { \
    GLOAD16(A + (size_t)(row0 + rS) * 512 + (kk) + tk, &lA[sel][tid * 8]); \
    GLOAD16(BT + (size_t)(c0 + rS) * 512 + (kk) + tk, &lB[sel][0][tid * 8]); \
    GLOAD16(BT + (size_t)(c0 + 256 + rS) * 512 + (kk) + tk, &lB[sel][1][tid * 8]); \
    GLOAD16(BT + (size_t)(c0 + 512 + rS) * 512 + (kk) + tk, &lB[sel][2][tid * 8]); \
} while (0)

    int sw = (g4 ^ (r & 3)) << 3;

#define COMPUTE3(cur) do { \
    half8 a_[2], b_[3][2]; \
    _Pragma("unroll") \
    for (int mi = 0; mi < 2; ++mi) \
        a_[mi] = *(const half8*)&lA[cur][(wm * 32 + mi * 16 + r) * 32 + sw]; \
    _Pragma("unroll") \
    for (int q = 0; q < 3; ++q) \
        _Pragma("unroll") \
        for (int ni = 0; ni < 2; ++ni) \
            b_[q][ni] = *(const half8*)&lB[cur][q][(wn * 32 + ni * 16 + r) * 32 + sw]; \
    _Pragma("unroll") \
    for (int q = 0; q < 3; ++q) \
        _Pragma("unroll") \
        for (int mi = 0; mi < 2; ++mi) \
            _Pragma("unroll") \
            for (int ni = 0; ni < 2; ++ni) \
                acc[q][mi][ni] = __builtin_amdgcn_mfma_f32_16x16x32_f16(a_[mi], b_[q][ni], acc[q][mi][ni], 0, 0, 0); \
} while (0)

    constexpr int NT = 16;  // 512/32
    STAGE3(0, 0);
    STAGE3(1, 32);
    for (int t = 0; t < NT - 1; ++t) {
        asm volatile("s_waitcnt vmcnt(4)" ::: "memory");
        __builtin_amdgcn_s_barrier();
        if (t + 2 < NT) STAGE3((t + 2) % 3, (t + 2) * 32);
        COMPUTE3(t % 3);
    }
    asm volatile("s_waitcnt vmcnt(0)" ::: "memory");
    __builtin_amdgcn_s_barrier();
    COMPUTE3((NT - 1) % 3);
#undef STAGE3
#undef COMPUTE3

    // fused tail: per (mi, reg): val[p] = sum_{ni, collanes} tanh-fuse * Wo
    #pragma unroll
    for (int mi = 0; mi < 2; ++mi) {
        float v0[4] = {}, v1[4] = {}, v2[4] = {};
        #pragma unroll
        for (int ni = 0; ni < 2; ++ni) {
            int ch = c0 + wn * 32 + ni * 16 + r;
            float b1 = fb1[ch], b2 = fb2[ch], b3 = fb3[ch];
            float w0 = Wo[ch * 3 + 0], w1 = Wo[ch * 3 + 1], w2 = Wo[ch * 3 + 2];
            #pragma unroll
            for (int j = 0; j < 4; ++j) {
                float g = 1.f / (1.f + expf(-(acc[0][mi][ni][j] + b1)));
                float a2 = acc[1][mi][ni][j] + b2;
                float a3 = acc[2][mi][ni][j] + b3;
                float fused = tanhf(g * a2 + (1.f - g) * a3);
                v0[j] += fused * w0;
                v1[j] += fused * w1;
                v2[j] += fused * w2;
            }
        }
        // reduce over the 16 col-lanes
        #pragma unroll
        for (int off = 1; off < 16; off <<= 1) {
            #pragma unroll
            for (int j = 0; j < 4; ++j) {
                v0[j] += __shfl_xor(v0[j], off, 64);
                v1[j] += __shfl_xor(v1[j], off, 64);
                v2[j] += __shfl_xor(v2[j], off, 64);
            }
        }
        if (r == 0) {
            int rowb = row0 + wm * 32 + mi * 16 + g4 * 4;
            #pragma unroll
            for (int j = 0; j < 4; ++j) {
                atomicAdd(&out[(size_t)(rowb + j) * 3 + 0], v0[j]);
                atomicAdd(&out[(size_t)(rowb + j) * 3 + 1], v1[j]);
                atomicAdd(&out[(size_t)(rowb + j) * 3 + 2], v2[j]);
            }
        }
    }
}

// ---------------- layer-1 epilogue (fp16 in) -> HLh ----------------
__global__ __launch_bounds__(256) void epi1_kernel(
    const unsigned short* __restrict__ Y1, const float* __restrict__ x,
    const float* __restrict__ bg1, const float* __restrict__ bf1, const float* __restrict__ bs1,
    const float* __restrict__ lg, const float* __restrict__ lb,
    const float* __restrict__ wsk, const float* __restrict__ bsk,
    unsigned short* __restrict__ HLh) {
    int node = blockIdx.x, o = threadIdx.x;
    __shared__ float red[8];
    size_t base = (size_t)node * 768;
    float g = h2f(Y1[base + o]) + bg1[o];
    float f = h2f(Y1[base + 256 + o]) + bf1[o];
    float s = h2f(Y1[base + 512 + o]) + bs1[o];
    float gate = 1.f / (1.f + expf(-g));
    float y = gate * f + (1.f - gate) * s;
    float a = y, bb = y * y;
    #pragma unroll
    for (int off = 32; off > 0; off >>= 1) { a += __shfl_xor(a, off, 64); bb += __shfl_xor(bb, off, 64); }
    int w = o >> 6, l = o & 63;
    if (l == 0) { red[w] = a; red[4 + w] = bb; }
    __syncthreads();
    float sum = red[0] + red[1] + red[2] + red[3];
    float sq = red[4] + red[5] + red[6] + red[7];
    float mean = sum * (1.f / 256.f);
    float var = sq * (1.f / 256.f) - mean * mean;
    float v = (y - mean) * rsqrtf(var + 1e-5f) * lg[o] + lb[o];
    v = fmaxf(v, 0.f);
    float x0 = x[(size_t)(node * 12 + 11) * 2];
    float x1 = x[(size_t)(node * 12 + 11) * 2 + 1];
    float res = x0 * wsk[o] + x1 * wsk[256 + o] + bsk[o];
    HLh[(size_t)node * 256 + o] = f2h(v + res);
}

// ---------------- fused GAT: one block per node, 1 barrier, short2 gathers ----------------
__global__ __launch_bounds__(256) void gat_kernel(
    const unsigned short* __restrict__ Y2, const float* __restrict__ ef,
    const int* __restrict__ fei, const float* __restrict__ AeS,
    const int* __restrict__ cnt, const int* __restrict__ idxs, const float* __restrict__ logv,
    unsigned short* __restrict__ Uh) {
    int node = blockIdx.x;
    int b = node / 400, n = node % 400;
    int tid = threadIdx.x;
    __shared__ int snd[9];
    __shared__ float alf[9][8];
    __shared__ float invdf[8];
    __shared__ int jidx[64];
    __shared__ float sca[64][8];
    __shared__ float alb[64][8];
    __shared__ float invda[8];
    __shared__ float svf[9][8];
    int c = cnt[n];

    if (tid < 64) {
        // ======== WAVE 0: fixed scores + softmax (wave-synchronous) ========
        int lane = tid;
        if (lane < 9) snd[lane] = fei[LL + n * 9 + lane];
        for (int e = lane; e < 72; e += 64) {
            int j = e >> 3, h = e & 7;
            int l = n * 9 + j;
            float e0 = ef[((size_t)b * LL + l) * 2];
            float e1 = ef[((size_t)b * LL + l) * 2 + 1];
            float ae = e0 * AeS[h] + e1 * AeS[8 + h];
            float aq = h2f(Y2[(size_t)node * 640 + 512 + h]);
            float ak = h2f(Y2[((size_t)(b * 400 + snd[j])) * 640 + 520 + h]);
            float s = aq + ak + ae;
            svf[j][h] = s > 0.f ? s : 0.2f * s;
        }
        if (lane < 8) {
            int h = lane;
            float mx = -1e30f;
            #pragma unroll
            for (int j = 0; j < 9; j++) mx = fmaxf(mx, svf[j][h]);
            float den = 0.f;
            #pragma unroll
            for (int j = 0; j < 9; j++) { float e = expf(svf[j][h] - mx); alf[j][h] = e; den += e; }
            invdf[h] = 1.f / fmaxf(den, 1e-12f);
        }
    } else if (tid < 128) {
        // ======== WAVE 1: adaptive scores + wave-local softmax ========
        int lane = tid - 64;
        if (lane < c) jidx[lane] = idxs[n * 64 + lane];
        float jl = (lane < c) ? logv[n * 64 + lane] : 0.f;
        for (int e = lane; e < c * 8; e += 64) {
            int j = e >> 3, h = e & 7;
            float aq = h2f(Y2[(size_t)node * 640 + 528 + h]);
            float ak = h2f(Y2[((size_t)(b * 400 + jidx[j])) * 640 + 536 + h]);
            float s = aq + ak;
            s = s > 0.f ? s : 0.2f * s;
            sca[j][h] = s + __shfl(jl, j, 64);
        }
        int h = lane >> 3, grp = lane & 7;
        float mx = -1e30f;
        for (int j = grp; j < c; j += 8) mx = fmaxf(mx, sca[j][h]);
        #pragma unroll
        for (int o = 1; o < 8; o <<= 1) mx = fmaxf(mx, __shfl_xor(mx, o, 64));
        float s = 0.f;
        for (int j = grp; j < c; j += 8) { float e = expf(sca[j][h] - mx); alb[j][h] = e; s += e; }
        #pragma unroll
        for (int o = 1; o < 8; o <<= 1) s += __shfl_xor(s, o, 64);
        if (grp == 0) invda[h] = 1.f / s;
    }
    __syncthreads();

    if (tid < 128) {
        int ch = tid * 2;
        int h = ch >> 5;
        float a0 = 0.f, a1 = 0.f;
        #pragma unroll
        for (int j = 0; j < 9; j++) {
            unsigned v = *(const unsigned*)&Y2[((size_t)(b * 400 + snd[j])) * 640 + ch];
            float al = alf[j][h];
            a0 += al * h2f((unsigned short)(v & 0xffff));
            a1 += al * h2f((unsigned short)(v >> 16));
        }
        float iv = invdf[h];
        a0 *= iv; a1 *= iv;
        a0 = a0 > 0.f ? a0 : (expf(a0) - 1.f);
        a1 = a1 > 0.f ? a1 : (expf(a1) - 1.f);
        unsigned o = (unsigned)f2h(a0) | ((unsigned)f2h(a1) << 16);
        *(unsigned*)&Uh[(size_t)node * 512 + ch] = o;
    } else {
        int ch = (tid - 128) * 2;
        int h = ch >> 5;
        float a0 = 0.f, a1 = 0.f;
        for (int j = 0; j < c; j++) {
            unsigned v = *(const unsigned*)&Y2[((size_t)(b * 400 + jidx[j])) * 640 + 256 + ch];
            float al = alb[j][h];
            a0 += al * h2f((unsigned short)(v & 0xffff));
            a1 += al * h2f((unsigned short)(v >> 16));
        }
        float iv = invda[h];
        a0 *= iv; a1 *= iv;
        a0 = a0 > 0.f ? a0 : (expf(a0) - 1.f);
        a1 = a1 > 0.f ? a1 : (expf(a1) - 1.f);
        unsigned o = (unsigned)f2h(a0) | ((unsigned)f2h(a1) << 16);
        *(unsigned*)&Uh[(size_t)node * 512 + 256 + ch] = o;
    }
}

// ---------------- launcher ----------------
extern "C" void kernel_launch(void* const* d_in, const int* in_sizes, int n_in,
                              void* d_out, int out_size, void* d_ws, size_t ws_size,
                              hipStream_t stream) {
    const float* x   = (const float*)d_in[0];
    const float* ef  = (const float*)d_in[1];
    const int*   fei = (const int*)d_in[2];
    const float* wg0 = (const float*)d_in[3];
    const float* bg0 = (const float*)d_in[4];
    const float* wf0 = (const float*)d_in[5];
    const float* bf0 = (const float*)d_in[6];
    const float* ws0 = (const float*)d_in[7];
    const float* bs0 = (const float*)d_in[8];
    const float* ln0g = (const float*)d_in[9];
    const float* ln0b = (const float*)d_in[10];
    const float* wg1 = (const float*)d_in[11];
    const float* bg1 = (const float*)d_in[12];
    const float* wf1 = (const float*)d_in[13];
    const float* bf1 = (const float*)d_in[14];
    const float* ws1 = (const float*)d_in[15];
    const float* bs1 = (const float*)d_in[16];
    const float* ln1g = (const float*)d_in[17];
    const float* ln1b = (const float*)d_in[18];
    const float* wsk = (const float*)d_in[19];
    const float* bsk = (const float*)d_in[20];
    const float* sWq = (const float*)d_in[21];
    const float* sWk = (const float*)d_in[22];
    const float* sWv = (const float*)d_in[23];
    const float* sWe = (const float*)d_in[24];
    const float* saq = (const float*)d_in[25];
    const float* sak = (const float*)d_in[26];
    const float* sae = (const float*)d_in[27];
    const float* dWq = (const float*)d_in[28];
    const float* dWk = (const float*)d_in[29];
    const float* dWv = (const float*)d_in[30];
    const float* daq = (const float*)d_in[31];
    const float* dak = (const float*)d_in[32];
    const float* E1  = (const float*)d_in[33];
    const float* E2  = (const float*)d_in[34];
    const float* fW1 = (const float*)d_in[35];
    const float* fb1 = (const float*)d_in[36];
    const float* fW2 = (const float*)d_in[37];
    const float* fb2 = (const float*)d_in[38];
    const float* fW3 = (const float*)d_in[39];
    const float* fb3 = (const float*)d_in[40];
    const float* Wo  = (const float*)d_in[41];
    const float* bo  = (const float*)d_in[42];
    float* out = (float*)d_out;

    char* b = (char*)d_ws;
    unsigned short* Xh  = (unsigned short*)(b + 0);          // 9,830,400
    unsigned short* Yh  = (unsigned short*)(b + 9830400);    // 9,830,400 (Y1/Y2 fp16, reused)
    unsigned short* HLh = (unsigned short*)(b + 19660800);   // 3,276,800
    unsigned short* Uh  = (unsigned short*)(b + 22937600);   // 6,553,600
    unsigned short* W1h = (unsigned short*)(b + 29491200);   // 1,179,648
    unsigned short* W2h = (unsigned short*)(b + 30670848);   // 327,680
    unsigned short* W3h = (unsigned short*)(b + 30998528);   // 786,432
    float*          AES = (float*)(b + 31784960);            // 64 (+pad)
    float*          LOGV= (float*)(b + 31785216);            // 102,400
    int*            CNT = (int*)(b + 31887616);              // 1,600
    int*            IDX = (int*)(b + 31889216);              // 102,400

    // all input-only work + out bias-init in ONE launch
    prep_kernel<<<6256, 256, 0, stream>>>(
        wg1, wf1, ws1,
        sWv, dWv, sWq, saq, sWk, sak, dWq, daq, dWk, dak,
        fW1, fW2, fW3, sWe, sae, E1, E2,
        x, wg0, bg0, wf0, bf0, ws0, bs0, ln0g, ln0b, bo,
        W1h, W2h, W3h, AES,
        CNT, IDX, LOGV, Xh, out);

    // G1: Y1 = X @ W1  (M=6400, N=768, K=768) -> fp16
    gemm_f16<768, 768, 12><<<dim3(12, 100), 256, 0, stream>>>(Xh, W1h, Yh);

    epi1_kernel<<<NODES, 256, 0, stream>>>(Yh, x, bg1, bf1, bs1, ln1g, ln1b, wsk, bsk, HLh);

    // G2: Y2 = HL @ W2 (M=6400, N=576 used, K=256) -> fp16 (reuses Yh after epi1)
    gemm_f16<256, 640, 9><<<dim3(9, 100), 256, 0, stream>>>(HLh, W2h, Yh);

    // fused attention stages -> U (one block per node)
    gat_kernel<<<NODES, 256, 0, stream>>>(Yh, ef, fei, AES, CNT, IDX, LOGV, Uh);

    // G3 + fused tail: out += tanh-fuse(U @ W3) @ Wo   (out pre-init'd with bo)
    gemm3_fused<<<dim3(4, 100), 256, 0, stream>>>(Uh, W3h, fb1, fb2, fb3, Wo, out);
}